// Round 21
// baseline (498.735 us; speedup 1.0000x reference)
//
#include <hip/hip_runtime.h>
#include <hip/hip_bf16.h>
#include <math.h>
#include <stddef.h>

#define EPS 1e-5f
#define F_IN 128
#define FE 32

// prm layout (float offsets)
#define P_M1 0
#define P_M2 256
#define P_C1 512
#define P_C2 528
#define P_CU 544
#define P_CV 560
#define P_WF 576
#define P_BO 704

// ---- bf16 helpers ----
__device__ __forceinline__ float bf2f(unsigned short u) {
    return __uint_as_float(((unsigned int)u) << 16);
}
__device__ __forceinline__ unsigned short f2bf(float f) {
    unsigned int u = __float_as_uint(f);
    u = (u + 0x7fffu + ((u >> 16) & 1u)) >> 16;
    return (unsigned short)u;
}
__device__ __forceinline__ unsigned int pack2(float a, float b) {
    return (unsigned int)f2bf(a) | ((unsigned int)f2bf(b) << 16);
}
__device__ __forceinline__ float lo16(unsigned int w) { return __uint_as_float(w << 16); }
__device__ __forceinline__ float hi16(unsigned int w) { return __uint_as_float(w & 0xffff0000u); }

// ---------------- degree (int counts) ----------------
__global__ __launch_bounds__(256) void k_deg(const int* __restrict__ src, const int* __restrict__ dst,
                                             int* __restrict__ dout, int* __restrict__ din, int E) {
    int e = blockIdx.x * 256 + threadIdx.x;
    if (e < E) {
        atomicAdd(&dout[src[e]], 1);
        atomicAdd(&din[dst[e]], 1);
    }
}

// ---------------- parallel scan phase A: per-block sums (coalesced) ----------------
__global__ __launch_bounds__(256) void k_scanA(const int* __restrict__ deg, int* __restrict__ bsum, int N) {
    int i = blockIdx.x * 256 + threadIdx.x;
    int v = (i < N) ? deg[i] : 0;
    #pragma unroll
    for (int m = 1; m < 64; m <<= 1) v += __shfl_xor(v, m, 64);
    __shared__ int red[4];
    if ((threadIdx.x & 63) == 0) red[threadIdx.x >> 6] = v;
    __syncthreads();
    if (threadIdx.x == 0) bsum[blockIdx.x] = red[0] + red[1] + red[2] + red[3];
}

// ---------------- phase B: 1-block exclusive scan of block sums; also emits bucket cursors ----------------
__global__ __launch_bounds__(256) void k_scanB(int* __restrict__ bsum, int NB, int* __restrict__ rowN,
                                               int* __restrict__ bcur) {
    __shared__ int s[256];
    int per = (NB + 255) >> 8;
    int start = threadIdx.x * per;
    int end = start + per; if (end > NB) end = NB; if (start > NB) start = NB;
    int sum = 0;
    for (int i = start; i < end; ++i) sum += bsum[i];
    s[threadIdx.x] = sum;
    __syncthreads();
    for (int off = 1; off < 256; off <<= 1) {
        int t = (threadIdx.x >= off) ? s[threadIdx.x - off] : 0;
        __syncthreads();
        s[threadIdx.x] += t;
        __syncthreads();
    }
    int run = (threadIdx.x == 0) ? 0 : s[threadIdx.x - 1];
    for (int i = start; i < end; ++i) {
        int v = bsum[i];
        bsum[i] = run;
        bcur[i] = run;   // bucket b starts at exclusive prefix of its 256-node block
        run += v;
    }
    if (threadIdx.x == 255) rowN[0] = s[255];
}

// ---------------- phase C: per-block LDS scan + block offset -> row, cursor ----------------
__global__ __launch_bounds__(256) void k_scanC(const int* __restrict__ deg, const int* __restrict__ boff,
                                               int* __restrict__ row, int* __restrict__ cursor, int N) {
    __shared__ int s[256];
    int i = blockIdx.x * 256 + threadIdx.x;
    int v = (i < N) ? deg[i] : 0;
    s[threadIdx.x] = v;
    __syncthreads();
    for (int off = 1; off < 256; off <<= 1) {
        int t = (threadIdx.x >= off) ? s[threadIdx.x - off] : 0;
        __syncthreads();
        s[threadIdx.x] += t;
        __syncthreads();
    }
    int r = boff[blockIdx.x] + s[threadIdx.x] - v;
    if (i < N) { row[i] = r; cursor[i] = r; }
}

// ---------------- bin pass: group (src,dst) pairs by dst-bucket, coalesced writes ----------------
__global__ __launch_bounds__(256) void k_bin(const int* __restrict__ src, const int* __restrict__ dst,
                                             int* __restrict__ bcur, uint2* __restrict__ binned,
                                             int E, int nBlocks) {
    __shared__ int hist[256], base[256], offs[256];
    int chunk = (E + nBlocks - 1) / nBlocks;
    int start = blockIdx.x * chunk;
    int end = start + chunk; if (end > E) end = E;
    hist[threadIdx.x] = 0; offs[threadIdx.x] = 0;
    __syncthreads();
    for (int i = start + threadIdx.x; i < end; i += 256)
        atomicAdd(&hist[dst[i] >> 8], 1);
    __syncthreads();
    int h = hist[threadIdx.x];
    base[threadIdx.x] = h ? atomicAdd(&bcur[threadIdx.x], h) : 0;
    __syncthreads();
    for (int i = start + threadIdx.x; i < end; i += 256) {
        int d = dst[i], b = d >> 8;
        int p = base[b] + atomicAdd(&offs[b], 1);
        binned[p] = make_uint2((unsigned int)src[i], (unsigned int)d);
    }
}

// ---------------- scatter pass: one WG per bucket, LDS cursors, L2-local writes ----------------
__global__ __launch_bounds__(256) void k_scat(const uint2* __restrict__ binned, const int* __restrict__ row,
                                              int* __restrict__ sorted_src, int N) {
    __shared__ int cur[256];
    int nb = blockIdx.x << 8;
    int hi = nb + 256; if (hi > N) hi = N;
    if (nb + threadIdx.x < N) cur[threadIdx.x] = row[nb + threadIdx.x];
    __syncthreads();
    int eStart = row[nb], eEnd = row[hi];
    for (int i = eStart + threadIdx.x; i < eEnd; i += 256) {
        uint2 p = binned[i];
        int pos = atomicAdd(&cur[(int)p.y - nb], 1);
        sorted_src[pos] = (int)p.x;
    }
}

// ---------------- counting-sort fallback (no-bin path) ----------------
__global__ __launch_bounds__(256) void k_sortedges(const int* __restrict__ src, const int* __restrict__ dst,
                                                   int* __restrict__ cursor, int* __restrict__ sorted_src, int E) {
    int e = blockIdx.x * 256 + threadIdx.x;
    if (e < E) {
        int p = atomicAdd(&cursor[dst[e]], 1);
        sorted_src[p] = src[e];
    }
}

// ---------------- s1 = (n_feats @ W1) * rsqrt(deg_out)  (bf16 out) ----------------
__global__ __launch_bounds__(256) void k_s1(const float* __restrict__ x, const float* __restrict__ W1,
                                            const int* __restrict__ dout, unsigned short* __restrict__ s1b, int N) {
    __shared__ float w[F_IN * 16];
    for (int i = threadIdx.x; i < F_IN * 16; i += 256) w[i] = W1[i];
    __syncthreads();
    int t = blockIdx.x * 256 + threadIdx.x;
    int n = t >> 4, j = t & 15;
    if (n >= N) return;
    const float* row = x + (size_t)n * F_IN;
    float acc = 0.f;
    #pragma unroll 8
    for (int k = 0; k < F_IN; ++k) acc += row[k] * w[k * 16 + j];
    s1b[(size_t)n * 16 + j] = f2bf(acc * rsqrtf(fmaxf((float)dout[n], 1.0f)));
}

// ---------------- vectorized agg1: 4 lanes/node x 4ch, uint2 gather; relu + BN1 stats ----------------
__global__ __launch_bounds__(256) void k_agg1v(const unsigned short* __restrict__ s1b,
                                               const int* __restrict__ sorted_src, const int* __restrict__ row,
                                               const int* __restrict__ din, const float* __restrict__ b1,
                                               float* __restrict__ h1, float* __restrict__ st1, int N) {
    __shared__ float lsum[16], lsq[16];
    if (threadIdx.x < 16) { lsum[threadIdx.x] = 0.f; lsq[threadIdx.x] = 0.f; }
    __syncthreads();
    int t = blockIdx.x * 256 + threadIdx.x;
    int n = t >> 2, q = t & 3;
    float v0 = 0.f, v1 = 0.f, v2 = 0.f, v3 = 0.f;
    if (n < N) {
        float a0 = 0.f, a1 = 0.f, a2 = 0.f, a3 = 0.f;
        int b = row[n], e = row[n + 1];
        for (int i = b; i < e; ++i) {
            int s = sorted_src[i];
            uint2 w = *(const uint2*)(s1b + (size_t)s * 16 + q * 4);
            a0 += lo16(w.x); a1 += hi16(w.x);
            a2 += lo16(w.y); a3 += hi16(w.y);
        }
        float div = rsqrtf(fmaxf((float)din[n], 1.f));
        v0 = fmaxf(a0 * div + b1[q * 4 + 0], 0.f);
        v1 = fmaxf(a1 * div + b1[q * 4 + 1], 0.f);
        v2 = fmaxf(a2 * div + b1[q * 4 + 2], 0.f);
        v3 = fmaxf(a3 * div + b1[q * 4 + 3], 0.f);
        *(float4*)(h1 + (size_t)n * 16 + q * 4) = make_float4(v0, v1, v2, v3);
    }
    float s0 = v0, s1 = v1, s2 = v2, s3 = v3;
    float q0 = v0 * v0, q1 = v1 * v1, q2 = v2 * v2, q3 = v3 * v3;
    #pragma unroll
    for (int m = 4; m < 64; m <<= 1) {
        s0 += __shfl_xor(s0, m, 64); q0 += __shfl_xor(q0, m, 64);
        s1 += __shfl_xor(s1, m, 64); q1 += __shfl_xor(q1, m, 64);
        s2 += __shfl_xor(s2, m, 64); q2 += __shfl_xor(q2, m, 64);
        s3 += __shfl_xor(s3, m, 64); q3 += __shfl_xor(q3, m, 64);
    }
    if ((threadIdx.x & 63) < 4) {
        int j = (threadIdx.x & 3) * 4;
        atomicAdd(&lsum[j + 0], s0); atomicAdd(&lsq[j + 0], q0);
        atomicAdd(&lsum[j + 1], s1); atomicAdd(&lsq[j + 1], q1);
        atomicAdd(&lsum[j + 2], s2); atomicAdd(&lsq[j + 2], q2);
        atomicAdd(&lsum[j + 3], s3); atomicAdd(&lsq[j + 3], q3);
    }
    __syncthreads();
    if (threadIdx.x < 16) {
        atomicAdd(&st1[threadIdx.x], lsum[threadIdx.x]);
        atomicAdd(&st1[16 + threadIdx.x], lsq[threadIdx.x]);
    }
}

// ---------------- fold BN1 + W2 + Wp1 slices into M1,M2 + vectors ----------------
__global__ __launch_bounds__(256) void k_fold(const float* __restrict__ st, const float* __restrict__ g1,
                                              const float* __restrict__ be1, const float* __restrict__ W2,
                                              const float* __restrict__ b2, const float* __restrict__ Wp1,
                                              float* __restrict__ prm, int N) {
    __shared__ float scale[16], shift[16], d2[64];
    int t = threadIdx.x;
    if (t < 16) {
        float mu = st[t] / (float)N;
        float var = st[16 + t] / (float)N - mu * mu;
        float sc = g1[t] * rsqrtf(var + EPS);
        scale[t] = sc;
        shift[t] = be1[t] - mu * sc;
    }
    __syncthreads();
    if (t < 64) {
        float acc = 0.f;
        #pragma unroll
        for (int j = 0; j < 16; ++j) acc += shift[j] * W2[j * 64 + t];
        d2[t] = acc;
    }
    __syncthreads();
    {
        int j1 = t >> 4, j2 = t & 15;
        float m1 = 0.f, m2 = 0.f;
        float sc = scale[j1];
        for (int c = 0; c < 64; ++c) {
            float w = sc * W2[j1 * 64 + c];
            m1 += w * Wp1[(32 + c) * 16 + j2];
            m2 += w * Wp1[(96 + c) * 16 + j2];
        }
        prm[P_M1 + j1 * 16 + j2] = m1;
        prm[P_M2 + j1 * 16 + j2] = m2;
    }
    if (t < 16) {
        float a = 0.f, b = 0.f, u = 0.f, v = 0.f;
        for (int c = 0; c < 64; ++c) {
            float wb = Wp1[(32 + c) * 16 + t], wc = Wp1[(96 + c) * 16 + t];
            a += d2[c] * wb; b += d2[c] * wc;
            u += b2[c] * wb; v += b2[c] * wc;
        }
        prm[P_C1 + t] = a; prm[P_C2 + t] = b;
        prm[P_CU + t] = u; prm[P_CV + t] = v;
    }
}

// ---------------- t12 = rsqrt(deg_out)*(h1@M1+c1) || (h1@M2+c2)  (interleaved 32 bf16/node) ----------------
__global__ __launch_bounds__(256) void k_t(const float* __restrict__ h1, const int* __restrict__ dout,
                                           const float* __restrict__ prm, unsigned short* __restrict__ t12b, int N) {
    __shared__ float M1[256], M2[256], c1[16], c2[16];
    for (int i = threadIdx.x; i < 256; i += 256) { M1[i] = prm[P_M1 + i]; M2[i] = prm[P_M2 + i]; }
    if (threadIdx.x < 16) { c1[threadIdx.x] = prm[P_C1 + threadIdx.x]; c2[threadIdx.x] = prm[P_C2 + threadIdx.x]; }
    __syncthreads();
    int t = blockIdx.x * 256 + threadIdx.x;
    int n = t >> 4, j = t & 15;
    if (n >= N) return;
    float div = rsqrtf(fmaxf((float)dout[n], 1.f));
    const float* h = h1 + (size_t)n * 16;
    float a = c1[j], b = c2[j];
    #pragma unroll
    for (int k = 0; k < 16; ++k) { float x = h[k]; a += x * M1[k * 16 + j]; b += x * M2[k * 16 + j]; }
    t12b[(size_t)n * 32 + j] = f2bf(a * div);
    t12b[(size_t)n * 32 + 16 + j] = f2bf(b * div);
}

// ---------------- vectorized agg2: 4 lanes/node x 8ch of 32, uint4 gather -> U,V bf16 ----------------
__global__ __launch_bounds__(256) void k_agg2v(const unsigned short* __restrict__ t12b,
                                               const int* __restrict__ sorted_src, const int* __restrict__ row,
                                               const int* __restrict__ din, const float* __restrict__ prm,
                                               unsigned short* __restrict__ Ub, unsigned short* __restrict__ Vb,
                                               int N) {
    int t = blockIdx.x * 256 + threadIdx.x;
    int n = t >> 2, q = t & 3;
    if (n >= N) return;
    float a0 = 0.f, a1 = 0.f, a2 = 0.f, a3 = 0.f, a4 = 0.f, a5 = 0.f, a6 = 0.f, a7 = 0.f;
    int b = row[n], e = row[n + 1];
    for (int i = b; i < e; ++i) {
        int s = sorted_src[i];
        uint4 w = *(const uint4*)(t12b + (size_t)s * 32 + q * 8);
        a0 += lo16(w.x); a1 += hi16(w.x);
        a2 += lo16(w.y); a3 += hi16(w.y);
        a4 += lo16(w.z); a5 += hi16(w.z);
        a6 += lo16(w.w); a7 += hi16(w.w);
    }
    float div = rsqrtf(fmaxf((float)din[n], 1.f));
    const float* cb = prm + ((q < 2) ? P_CU : P_CV) + (q & 1) * 8;
    uint4 ov;
    ov.x = pack2(a0 * div + cb[0], a1 * div + cb[1]);
    ov.y = pack2(a2 * div + cb[2], a3 * div + cb[3]);
    ov.z = pack2(a4 * div + cb[4], a5 * div + cb[5]);
    ov.w = pack2(a6 * div + cb[6], a7 * div + cb[7]);
    unsigned short* dstp = ((q < 2) ? Ub : Vb) + (size_t)n * 16 + (q & 1) * 8;
    *(uint4*)dstp = ov;
}

// ---------------- edge pass 1: wave-local LDS staging + ds_read_b128, 8 waves/SIMD ----------------
// Round-19 structure (proven 134us at 4 waves/SIMD) with occupancy cap lifted: VGPR<=64 fits
// 8 waves/SIMD; grid 4096 blocks fills 8 blocks/CU. Latency-bound -> 2x resident waves.
__global__ __launch_bounds__(256, 8) void k_edge1(const float* __restrict__ ef, const int* __restrict__ src,
                                                  const int* __restrict__ dst, const float* __restrict__ Wp1,
                                                  const float* __restrict__ bp1,
                                                  const unsigned short* __restrict__ Ub,
                                                  const unsigned short* __restrict__ Vb,
                                                  unsigned short* __restrict__ z0h,
                                                  float* __restrict__ statsp, int E) {
    __shared__ float red[32];
    __shared__ __align__(16) float efs[4][4][36];   // [wave][edge][padded row]
    if (threadIdx.x < 32) red[threadIdx.x] = 0.f;
    __syncthreads();

    int l = threadIdx.x & 63;
    int w = threadIdx.x >> 6;
    int g = l >> 4, j = l & 15;

    float wcol[32];
    #pragma unroll
    for (int k = 0; k < 32; ++k) wcol[k] = Wp1[k * 16 + j];
    float bj = bp1[j];

    int wv = (blockIdx.x * 256 + threadIdx.x) >> 6;
    int nW = (gridDim.x * 256) >> 6;
    float sum = 0.f, sq = 0.f;

    #pragma unroll 1
    for (int base = wv * 4; base < E; base += nW * 4) {
        int e = base + g;
        float2 v = make_float2(0.f, 0.f);
        if (e < E) v = ((const float2*)(ef + (size_t)e * FE))[j];
        *(float2*)&efs[w][g][2 * j] = v;           // ds_write_b64, 2-way bank alias (free)
        if (e < E) {
            int s = src[e], d = dst[e];
            float z = bj + bf2f(Ub[s * 16 + j]) + bf2f(Vb[d * 16 + j]);
            #pragma unroll
            for (int q = 0; q < 8; ++q) {
                float4 x = *(const float4*)&efs[w][g][4 * q];   // ds_read_b128 broadcast
                z += x.x * wcol[4 * q + 0] + x.y * wcol[4 * q + 1]
                   + x.z * wcol[4 * q + 2] + x.w * wcol[4 * q + 3];
            }
            z0h[(size_t)e * 16 + j] = f2bf(z);
            sum += z; sq += z * z;
        }
    }

    sum += __shfl_xor(sum, 16, 64); sq += __shfl_xor(sq, 16, 64);
    sum += __shfl_xor(sum, 32, 64); sq += __shfl_xor(sq, 32, 64);
    if (l < 16) { atomicAdd(&red[j], sum); atomicAdd(&red[16 + j], sq); }
    __syncthreads();
    if (threadIdx.x < 16) {
        atomicAdd(&statsp[threadIdx.x], red[threadIdx.x]);
        atomicAdd(&statsp[16 + threadIdx.x], red[16 + threadIdx.x]);
    }
}

// ---------------- fold BN2 into Wp2 ----------------
__global__ __launch_bounds__(128) void k_fold2(const float* __restrict__ stp, const float* __restrict__ gp,
                                               const float* __restrict__ bep, const float* __restrict__ Wp2,
                                               const float* __restrict__ bp2, float* __restrict__ prm, int E) {
    __shared__ float sc[16], sh[16];
    int t = threadIdx.x;
    if (t < 16) {
        float mu = stp[t] / (float)E;
        float var = stp[16 + t] / (float)E - mu * mu;
        float s = gp[t] * rsqrtf(var + EPS);
        sc[t] = s;
        sh[t] = bep[t] - mu * s;
    }
    __syncthreads();
    if (t < 128) { int j = t >> 3, k = t & 7; prm[P_WF + t] = sc[j] * Wp2[j * 8 + k]; }
    if (t < 8) {
        float a = bp2[t];
        #pragma unroll
        for (int j = 0; j < 16; ++j) a += sh[j] * Wp2[j * 8 + t];
        prm[P_BO + t] = a;
    }
}

// ---------------- logits + log_softmax ----------------
__device__ __forceinline__ void logits_out(int e, const float* z, const float* wf, const float* bo,
                                           float* __restrict__ out) {
    float l[8];
    #pragma unroll
    for (int k = 0; k < 8; ++k) l[k] = bo[k];
    #pragma unroll
    for (int j = 0; j < 16; ++j) {
        float x = z[j];
        #pragma unroll
        for (int k = 0; k < 8; ++k) l[k] += x * wf[j * 8 + k];
    }
    float m = l[0];
    #pragma unroll
    for (int k = 1; k < 8; ++k) m = fmaxf(m, l[k]);
    float s = 0.f;
    #pragma unroll
    for (int k = 0; k < 8; ++k) s += expf(l[k] - m);
    float r = m + logf(s);
    float4* op = (float4*)(out + (size_t)e * 8);
    op[0] = make_float4(l[0] - r, l[1] - r, l[2] - r, l[3] - r);
    op[1] = make_float4(l[4] - r, l[5] - r, l[6] - r, l[7] - r);
}

// ---------------- edge pass 2 (read bf16 z0) ----------------
__global__ __launch_bounds__(256) void k_edge2(const unsigned int* __restrict__ z0b,
                                               const float* __restrict__ prm,
                                               float* __restrict__ out, int E) {
    __shared__ float wf[128], bo[8];
    if (threadIdx.x < 128) wf[threadIdx.x] = prm[P_WF + threadIdx.x];
    if (threadIdx.x < 8) bo[threadIdx.x] = prm[P_BO + threadIdx.x];
    __syncthreads();
    int e = blockIdx.x * 256 + threadIdx.x;
    if (e >= E) return;
    const uint4* zp = (const uint4*)(z0b + (size_t)e * 8);
    uint4 a0 = zp[0], a1 = zp[1];
    unsigned int w[8] = {a0.x, a0.y, a0.z, a0.w, a1.x, a1.y, a1.z, a1.w};
    float z[16];
    #pragma unroll
    for (int q = 0; q < 8; ++q) {
        z[2 * q]     = __uint_as_float(w[q] << 16);
        z[2 * q + 1] = __uint_as_float(w[q] & 0xffff0000u);
    }
    logits_out(e, z, wf, bo, out);
}

// ---------------- fallback (ws too small): LDS-staged edge1 stats-only + recompute pass 2 ----------------
__global__ __launch_bounds__(256, 8) void k_edge1_stats(const float* __restrict__ ef, const int* __restrict__ src,
                                                        const int* __restrict__ dst, const float* __restrict__ Wp1,
                                                        const float* __restrict__ bp1,
                                                        const unsigned short* __restrict__ Ub,
                                                        const unsigned short* __restrict__ Vb,
                                                        float* __restrict__ statsp, int E) {
    __shared__ float red[32];
    __shared__ __align__(16) float efs[4][4][36];
    if (threadIdx.x < 32) red[threadIdx.x] = 0.f;
    __syncthreads();
    int l = threadIdx.x & 63;
    int w = threadIdx.x >> 6;
    int g = l >> 4, j = l & 15;
    float wcol[32];
    #pragma unroll
    for (int k = 0; k < 32; ++k) wcol[k] = Wp1[k * 16 + j];
    float bj = bp1[j];
    int wv = (blockIdx.x * 256 + threadIdx.x) >> 6;
    int nW = (gridDim.x * 256) >> 6;
    float sum = 0.f, sq = 0.f;
    #pragma unroll 1
    for (int base = wv * 4; base < E; base += nW * 4) {
        int e = base + g;
        float2 v = make_float2(0.f, 0.f);
        if (e < E) v = ((const float2*)(ef + (size_t)e * FE))[j];
        *(float2*)&efs[w][g][2 * j] = v;
        if (e < E) {
            int s = src[e], d = dst[e];
            float z = bj + bf2f(Ub[s * 16 + j]) + bf2f(Vb[d * 16 + j]);
            #pragma unroll
            for (int q = 0; q < 8; ++q) {
                float4 x = *(const float4*)&efs[w][g][4 * q];
                z += x.x * wcol[4 * q + 0] + x.y * wcol[4 * q + 1]
                   + x.z * wcol[4 * q + 2] + x.w * wcol[4 * q + 3];
            }
            sum += z; sq += z * z;
        }
    }
    sum += __shfl_xor(sum, 16, 64); sq += __shfl_xor(sq, 16, 64);
    sum += __shfl_xor(sum, 32, 64); sq += __shfl_xor(sq, 32, 64);
    if (l < 16) { atomicAdd(&red[j], sum); atomicAdd(&red[16 + j], sq); }
    __syncthreads();
    if (threadIdx.x < 16) {
        atomicAdd(&statsp[threadIdx.x], red[threadIdx.x]);
        atomicAdd(&statsp[16 + threadIdx.x], red[16 + threadIdx.x]);
    }
}

__global__ __launch_bounds__(256, 2) void k_edge2_rc(const float* __restrict__ ef, const int* __restrict__ src,
                                                     const int* __restrict__ dst, const float* __restrict__ Wp1,
                                                     const float* __restrict__ bp1,
                                                     const unsigned short* __restrict__ Ub,
                                                     const unsigned short* __restrict__ Vb,
                                                     const float* __restrict__ prm,
                                                     float* __restrict__ out, int E) {
    __shared__ float wa[FE * 16];
    __shared__ float bb[16];
    __shared__ float wf[128], bo[8];
    for (int i = threadIdx.x; i < FE * 16; i += 256) wa[i] = Wp1[i];
    if (threadIdx.x < 16) bb[threadIdx.x] = bp1[threadIdx.x];
    if (threadIdx.x < 128) wf[threadIdx.x] = prm[P_WF + threadIdx.x];
    if (threadIdx.x < 8) bo[threadIdx.x] = prm[P_BO + threadIdx.x];
    __syncthreads();
    int e = blockIdx.x * 256 + threadIdx.x;
    if (e >= E) return;
    float z[16];
    {
        int s = src[e], d = dst[e];
        const uint4* up = (const uint4*)(Ub + (size_t)s * 16);
        const uint4* vp = (const uint4*)(Vb + (size_t)d * 16);
        #pragma unroll
        for (int h = 0; h < 2; ++h) {
            uint4 ua = up[h], va = vp[h];
            unsigned int uu[4] = {ua.x, ua.y, ua.z, ua.w};
            unsigned int vv[4] = {va.x, va.y, va.z, va.w};
            #pragma unroll
            for (int q = 0; q < 4; ++q) {
                int jj = h * 8 + 2 * q;
                z[jj]     = bb[jj]     + __uint_as_float(uu[q] << 16)          + __uint_as_float(vv[q] << 16);
                z[jj + 1] = bb[jj + 1] + __uint_as_float(uu[q] & 0xffff0000u) + __uint_as_float(vv[q] & 0xffff0000u);
            }
        }
    }
    const float4* ep = (const float4*)(ef + (size_t)e * FE);
    #pragma unroll
    for (int q = 0; q < 8; ++q) {
        float4 x4 = ep[q];
        float xs[4] = {x4.x, x4.y, x4.z, x4.w};
        #pragma unroll
        for (int kk = 0; kk < 4; ++kk) {
            float x = xs[kk];
            #pragma unroll
            for (int jj = 0; jj < 16; ++jj) z[jj] += x * wa[(q * 4 + kk) * 16 + jj];
        }
    }
    logits_out(e, z, wf, bo, out);
}

extern "C" void kernel_launch(void* const* d_in, const int* in_sizes, int n_in,
                              void* d_out, int out_size, void* d_ws, size_t ws_size,
                              hipStream_t stream) {
    const float* n_feats = (const float*)d_in[0];
    const float* e_feats = (const float*)d_in[1];
    const int*   src     = (const int*)d_in[2];
    const int*   dst     = (const int*)d_in[3];
    const float* W1      = (const float*)d_in[4];
    const float* b1      = (const float*)d_in[5];
    const float* g1      = (const float*)d_in[6];
    const float* be1     = (const float*)d_in[7];
    const float* W2      = (const float*)d_in[8];
    const float* b2      = (const float*)d_in[9];
    const float* Wp1     = (const float*)d_in[10];
    const float* bp1     = (const float*)d_in[11];
    const float* gp      = (const float*)d_in[12];
    const float* bep     = (const float*)d_in[13];
    const float* Wp2     = (const float*)d_in[14];
    const float* bp2     = (const float*)d_in[15];
    float* out = (float*)d_out;

    int N = in_sizes[0] / F_IN;
    int E = in_sizes[2];
    float* ws = (float*)d_ws;
    int NB = (N + 255) / 256;
    int BKT = (N + 255) >> 8;   // 256 nodes per bucket (== NB)

    size_t off = 0;
    auto take = [&](size_t n) { size_t r = off; off += (n + 15) & ~(size_t)15; return r; };
    size_t o_dout_i = take((size_t)N);
    size_t o_din_i  = take((size_t)N);
    size_t o_st1    = take(32);
    size_t o_stp    = take(32);
    size_t zeroUnits = off;
    size_t o_row    = take((size_t)N + 1);
    size_t o_cursor = take((size_t)N);
    size_t o_bsum   = take((size_t)NB);
    size_t o_bcur   = take(256);
    size_t o_sorted = take((size_t)E);
    size_t o_prm    = take(1024);
    size_t o_s1b    = take((size_t)8 * N);
    size_t o_h1     = take((size_t)16 * N);
    size_t o_t12b   = take((size_t)16 * N);
    size_t o_Ub     = take((size_t)8 * N);
    size_t o_Vb     = take((size_t)8 * N);
    size_t o_binned = take((size_t)2 * E);
    size_t o_z0b    = off;
    bool store_z = ws_size >= (off + (size_t)8 * E) * 4;
    bool use_bin = (BKT <= 256) && (ws_size >= off * 4);

    hipMemsetAsync(ws, 0, zeroUnits * 4, stream);

    int* dout_i = (int*)(ws + o_dout_i);
    int* din_i  = (int*)(ws + o_din_i);
    int* rowp   = (int*)(ws + o_row);
    int* curp   = (int*)(ws + o_cursor);
    int* bsump  = (int*)(ws + o_bsum);
    int* bcurp  = (int*)(ws + o_bcur);
    int* sortedp = (int*)(ws + o_sorted);
    uint2* binnedp = (uint2*)(ws + o_binned);
    unsigned short* s1b  = (unsigned short*)(ws + o_s1b);
    unsigned short* t12b = (unsigned short*)(ws + o_t12b);
    unsigned short* Ub   = (unsigned short*)(ws + o_Ub);
    unsigned short* Vb   = (unsigned short*)(ws + o_Vb);
    unsigned short* z0h  = (unsigned short*)(ws + o_z0b);
    unsigned int* z0b    = (unsigned int*)(ws + o_z0b);

    int bE = (E + 255) / 256;
    int bN16 = (N * 16 + 255) / 256;
    int bAgg = (N * 4 + 255) / 256;

    k_deg<<<bE, 256, 0, stream>>>(src, dst, dout_i, din_i, E);
    k_scanA<<<NB, 256, 0, stream>>>(din_i, bsump, N);
    k_scanB<<<1, 256, 0, stream>>>(bsump, NB, rowp + N, bcurp);
    k_scanC<<<NB, 256, 0, stream>>>(din_i, bsump, rowp, curp, N);
    if (use_bin) {
        k_bin<<<256, 256, 0, stream>>>(src, dst, bcurp, binnedp, E, 256);
        k_scat<<<BKT, 256, 0, stream>>>(binnedp, rowp, sortedp, N);
    } else {
        k_sortedges<<<bE, 256, 0, stream>>>(src, dst, curp, sortedp, E);
    }
    k_s1<<<bN16, 256, 0, stream>>>(n_feats, W1, dout_i, s1b, N);
    k_agg1v<<<bAgg, 256, 0, stream>>>(s1b, sortedp, rowp, din_i, b1, ws + o_h1, ws + o_st1, N);
    k_fold<<<1, 256, 0, stream>>>(ws + o_st1, g1, be1, W2, b2, Wp1, ws + o_prm, N);
    k_t<<<bN16, 256, 0, stream>>>(ws + o_h1, dout_i, ws + o_prm, t12b, N);
    k_agg2v<<<bAgg, 256, 0, stream>>>(t12b, sortedp, rowp, din_i, ws + o_prm, Ub, Vb, N);

    if (store_z) {
        // 8 waves/SIMD: 4096 blocks = 8 blocks/CU on 256 CUs
        k_edge1<<<4096, 256, 0, stream>>>(e_feats, src, dst, Wp1, bp1, Ub, Vb, z0h, ws + o_stp, E);
        k_fold2<<<1, 128, 0, stream>>>(ws + o_stp, gp, bep, Wp2, bp2, ws + o_prm, E);
        k_edge2<<<bE, 256, 0, stream>>>(z0b, ws + o_prm, out, E);
    } else {
        k_edge1_stats<<<4096, 256, 0, stream>>>(e_feats, src, dst, Wp1, bp1, Ub, Vb, ws + o_stp, E);
        k_fold2<<<1, 128, 0, stream>>>(ws + o_stp, gp, bep, Wp2, bp2, ws + o_prm, E);
        k_edge2_rc<<<bE, 256, 0, stream>>>(e_feats, src, dst, Wp1, bp1, Ub, Vb, ws + o_prm, out, E);
    }
}

// Round 22
// 443.017 us; speedup vs baseline: 1.1258x; 1.1258x over previous
//
#include <hip/hip_runtime.h>
#include <hip/hip_bf16.h>
#include <math.h>
#include <stddef.h>

#define EPS 1e-5f
#define F_IN 128
#define FE 32

// prm layout (float offsets)
#define P_M1 0
#define P_M2 256
#define P_C1 512
#define P_C2 528
#define P_CU 544
#define P_CV 560
#define P_WF 576
#define P_BO 704

// ---- bf16 helpers ----
__device__ __forceinline__ float bf2f(unsigned short u) {
    return __uint_as_float(((unsigned int)u) << 16);
}
__device__ __forceinline__ unsigned short f2bf(float f) {
    unsigned int u = __float_as_uint(f);
    u = (u + 0x7fffu + ((u >> 16) & 1u)) >> 16;
    return (unsigned short)u;
}
__device__ __forceinline__ unsigned int pack2(float a, float b) {
    return (unsigned int)f2bf(a) | ((unsigned int)f2bf(b) << 16);
}
__device__ __forceinline__ float lo16(unsigned int w) { return __uint_as_float(w << 16); }
__device__ __forceinline__ float hi16(unsigned int w) { return __uint_as_float(w & 0xffff0000u); }

// ---------------- degree (int counts) ----------------
__global__ __launch_bounds__(256) void k_deg(const int* __restrict__ src, const int* __restrict__ dst,
                                             int* __restrict__ dout, int* __restrict__ din, int E) {
    int e = blockIdx.x * 256 + threadIdx.x;
    if (e < E) {
        atomicAdd(&dout[src[e]], 1);
        atomicAdd(&din[dst[e]], 1);
    }
}

// ---------------- parallel scan phase A: per-block sums (coalesced) ----------------
__global__ __launch_bounds__(256) void k_scanA(const int* __restrict__ deg, int* __restrict__ bsum, int N) {
    int i = blockIdx.x * 256 + threadIdx.x;
    int v = (i < N) ? deg[i] : 0;
    #pragma unroll
    for (int m = 1; m < 64; m <<= 1) v += __shfl_xor(v, m, 64);
    __shared__ int red[4];
    if ((threadIdx.x & 63) == 0) red[threadIdx.x >> 6] = v;
    __syncthreads();
    if (threadIdx.x == 0) bsum[blockIdx.x] = red[0] + red[1] + red[2] + red[3];
}

// ---------------- phase B: 1-block exclusive scan of block sums; also emits bucket cursors ----------------
__global__ __launch_bounds__(256) void k_scanB(int* __restrict__ bsum, int NB, int* __restrict__ rowN,
                                               int* __restrict__ bcur) {
    __shared__ int s[256];
    int per = (NB + 255) >> 8;
    int start = threadIdx.x * per;
    int end = start + per; if (end > NB) end = NB; if (start > NB) start = NB;
    int sum = 0;
    for (int i = start; i < end; ++i) sum += bsum[i];
    s[threadIdx.x] = sum;
    __syncthreads();
    for (int off = 1; off < 256; off <<= 1) {
        int t = (threadIdx.x >= off) ? s[threadIdx.x - off] : 0;
        __syncthreads();
        s[threadIdx.x] += t;
        __syncthreads();
    }
    int run = (threadIdx.x == 0) ? 0 : s[threadIdx.x - 1];
    for (int i = start; i < end; ++i) {
        int v = bsum[i];
        bsum[i] = run;
        bcur[i] = run;   // bucket b starts at exclusive prefix of its 256-node block
        run += v;
    }
    if (threadIdx.x == 255) rowN[0] = s[255];
}

// ---------------- phase C: per-block LDS scan + block offset -> row, cursor ----------------
__global__ __launch_bounds__(256) void k_scanC(const int* __restrict__ deg, const int* __restrict__ boff,
                                               int* __restrict__ row, int* __restrict__ cursor, int N) {
    __shared__ int s[256];
    int i = blockIdx.x * 256 + threadIdx.x;
    int v = (i < N) ? deg[i] : 0;
    s[threadIdx.x] = v;
    __syncthreads();
    for (int off = 1; off < 256; off <<= 1) {
        int t = (threadIdx.x >= off) ? s[threadIdx.x - off] : 0;
        __syncthreads();
        s[threadIdx.x] += t;
        __syncthreads();
    }
    int r = boff[blockIdx.x] + s[threadIdx.x] - v;
    if (i < N) { row[i] = r; cursor[i] = r; }
}

// ---------------- bin pass: group (src,dst) pairs by dst-bucket, coalesced writes ----------------
__global__ __launch_bounds__(256) void k_bin(const int* __restrict__ src, const int* __restrict__ dst,
                                             int* __restrict__ bcur, uint2* __restrict__ binned,
                                             int E, int nBlocks) {
    __shared__ int hist[256], base[256], offs[256];
    int chunk = (E + nBlocks - 1) / nBlocks;
    int start = blockIdx.x * chunk;
    int end = start + chunk; if (end > E) end = E;
    hist[threadIdx.x] = 0; offs[threadIdx.x] = 0;
    __syncthreads();
    for (int i = start + threadIdx.x; i < end; i += 256)
        atomicAdd(&hist[dst[i] >> 8], 1);
    __syncthreads();
    int h = hist[threadIdx.x];
    base[threadIdx.x] = h ? atomicAdd(&bcur[threadIdx.x], h) : 0;
    __syncthreads();
    for (int i = start + threadIdx.x; i < end; i += 256) {
        int d = dst[i], b = d >> 8;
        int p = base[b] + atomicAdd(&offs[b], 1);
        binned[p] = make_uint2((unsigned int)src[i], (unsigned int)d);
    }
}

// ---------------- scatter pass: one WG per bucket, LDS cursors, L2-local writes ----------------
__global__ __launch_bounds__(256) void k_scat(const uint2* __restrict__ binned, const int* __restrict__ row,
                                              int* __restrict__ sorted_src, int N) {
    __shared__ int cur[256];
    int nb = blockIdx.x << 8;
    int hi = nb + 256; if (hi > N) hi = N;
    if (nb + threadIdx.x < N) cur[threadIdx.x] = row[nb + threadIdx.x];
    __syncthreads();
    int eStart = row[nb], eEnd = row[hi];
    for (int i = eStart + threadIdx.x; i < eEnd; i += 256) {
        uint2 p = binned[i];
        int pos = atomicAdd(&cur[(int)p.y - nb], 1);
        sorted_src[pos] = (int)p.x;
    }
}

// ---------------- counting-sort fallback (no-bin path) ----------------
__global__ __launch_bounds__(256) void k_sortedges(const int* __restrict__ src, const int* __restrict__ dst,
                                                   int* __restrict__ cursor, int* __restrict__ sorted_src, int E) {
    int e = blockIdx.x * 256 + threadIdx.x;
    if (e < E) {
        int p = atomicAdd(&cursor[dst[e]], 1);
        sorted_src[p] = src[e];
    }
}

// ---------------- s1 = (n_feats @ W1) * rsqrt(deg_out)  (bf16 out) ----------------
__global__ __launch_bounds__(256) void k_s1(const float* __restrict__ x, const float* __restrict__ W1,
                                            const int* __restrict__ dout, unsigned short* __restrict__ s1b, int N) {
    __shared__ float w[F_IN * 16];
    for (int i = threadIdx.x; i < F_IN * 16; i += 256) w[i] = W1[i];
    __syncthreads();
    int t = blockIdx.x * 256 + threadIdx.x;
    int n = t >> 4, j = t & 15;
    if (n >= N) return;
    const float* row = x + (size_t)n * F_IN;
    float acc = 0.f;
    #pragma unroll 8
    for (int k = 0; k < F_IN; ++k) acc += row[k] * w[k * 16 + j];
    s1b[(size_t)n * 16 + j] = f2bf(acc * rsqrtf(fmaxf((float)dout[n], 1.0f)));
}

// ---------------- vectorized agg1: 4 lanes/node x 4ch, uint2 gather; relu + BN1 stats ----------------
__global__ __launch_bounds__(256) void k_agg1v(const unsigned short* __restrict__ s1b,
                                               const int* __restrict__ sorted_src, const int* __restrict__ row,
                                               const int* __restrict__ din, const float* __restrict__ b1,
                                               float* __restrict__ h1, float* __restrict__ st1, int N) {
    __shared__ float lsum[16], lsq[16];
    if (threadIdx.x < 16) { lsum[threadIdx.x] = 0.f; lsq[threadIdx.x] = 0.f; }
    __syncthreads();
    int t = blockIdx.x * 256 + threadIdx.x;
    int n = t >> 2, q = t & 3;
    float v0 = 0.f, v1 = 0.f, v2 = 0.f, v3 = 0.f;
    if (n < N) {
        float a0 = 0.f, a1 = 0.f, a2 = 0.f, a3 = 0.f;
        int b = row[n], e = row[n + 1];
        for (int i = b; i < e; ++i) {
            int s = sorted_src[i];
            uint2 w = *(const uint2*)(s1b + (size_t)s * 16 + q * 4);
            a0 += lo16(w.x); a1 += hi16(w.x);
            a2 += lo16(w.y); a3 += hi16(w.y);
        }
        float div = rsqrtf(fmaxf((float)din[n], 1.f));
        v0 = fmaxf(a0 * div + b1[q * 4 + 0], 0.f);
        v1 = fmaxf(a1 * div + b1[q * 4 + 1], 0.f);
        v2 = fmaxf(a2 * div + b1[q * 4 + 2], 0.f);
        v3 = fmaxf(a3 * div + b1[q * 4 + 3], 0.f);
        *(float4*)(h1 + (size_t)n * 16 + q * 4) = make_float4(v0, v1, v2, v3);
    }
    float s0 = v0, s1 = v1, s2 = v2, s3 = v3;
    float q0 = v0 * v0, q1 = v1 * v1, q2 = v2 * v2, q3 = v3 * v3;
    #pragma unroll
    for (int m = 4; m < 64; m <<= 1) {
        s0 += __shfl_xor(s0, m, 64); q0 += __shfl_xor(q0, m, 64);
        s1 += __shfl_xor(s1, m, 64); q1 += __shfl_xor(q1, m, 64);
        s2 += __shfl_xor(s2, m, 64); q2 += __shfl_xor(q2, m, 64);
        s3 += __shfl_xor(s3, m, 64); q3 += __shfl_xor(q3, m, 64);
    }
    if ((threadIdx.x & 63) < 4) {
        int j = (threadIdx.x & 3) * 4;
        atomicAdd(&lsum[j + 0], s0); atomicAdd(&lsq[j + 0], q0);
        atomicAdd(&lsum[j + 1], s1); atomicAdd(&lsq[j + 1], q1);
        atomicAdd(&lsum[j + 2], s2); atomicAdd(&lsq[j + 2], q2);
        atomicAdd(&lsum[j + 3], s3); atomicAdd(&lsq[j + 3], q3);
    }
    __syncthreads();
    if (threadIdx.x < 16) {
        atomicAdd(&st1[threadIdx.x], lsum[threadIdx.x]);
        atomicAdd(&st1[16 + threadIdx.x], lsq[threadIdx.x]);
    }
}

// ---------------- fold BN1 + W2 + Wp1 slices into M1,M2 + vectors ----------------
__global__ __launch_bounds__(256) void k_fold(const float* __restrict__ st, const float* __restrict__ g1,
                                              const float* __restrict__ be1, const float* __restrict__ W2,
                                              const float* __restrict__ b2, const float* __restrict__ Wp1,
                                              float* __restrict__ prm, int N) {
    __shared__ float scale[16], shift[16], d2[64];
    int t = threadIdx.x;
    if (t < 16) {
        float mu = st[t] / (float)N;
        float var = st[16 + t] / (float)N - mu * mu;
        float sc = g1[t] * rsqrtf(var + EPS);
        scale[t] = sc;
        shift[t] = be1[t] - mu * sc;
    }
    __syncthreads();
    if (t < 64) {
        float acc = 0.f;
        #pragma unroll
        for (int j = 0; j < 16; ++j) acc += shift[j] * W2[j * 64 + t];
        d2[t] = acc;
    }
    __syncthreads();
    {
        int j1 = t >> 4, j2 = t & 15;
        float m1 = 0.f, m2 = 0.f;
        float sc = scale[j1];
        for (int c = 0; c < 64; ++c) {
            float w = sc * W2[j1 * 64 + c];
            m1 += w * Wp1[(32 + c) * 16 + j2];
            m2 += w * Wp1[(96 + c) * 16 + j2];
        }
        prm[P_M1 + j1 * 16 + j2] = m1;
        prm[P_M2 + j1 * 16 + j2] = m2;
    }
    if (t < 16) {
        float a = 0.f, b = 0.f, u = 0.f, v = 0.f;
        for (int c = 0; c < 64; ++c) {
            float wb = Wp1[(32 + c) * 16 + t], wc = Wp1[(96 + c) * 16 + t];
            a += d2[c] * wb; b += d2[c] * wc;
            u += b2[c] * wb; v += b2[c] * wc;
        }
        prm[P_C1 + t] = a; prm[P_C2 + t] = b;
        prm[P_CU + t] = u; prm[P_CV + t] = v;
    }
}

// ---------------- t12 = rsqrt(deg_out)*(h1@M1+c1) || (h1@M2+c2)  (interleaved 32 bf16/node) ----------------
__global__ __launch_bounds__(256) void k_t(const float* __restrict__ h1, const int* __restrict__ dout,
                                           const float* __restrict__ prm, unsigned short* __restrict__ t12b, int N) {
    __shared__ float M1[256], M2[256], c1[16], c2[16];
    for (int i = threadIdx.x; i < 256; i += 256) { M1[i] = prm[P_M1 + i]; M2[i] = prm[P_M2 + i]; }
    if (threadIdx.x < 16) { c1[threadIdx.x] = prm[P_C1 + threadIdx.x]; c2[threadIdx.x] = prm[P_C2 + threadIdx.x]; }
    __syncthreads();
    int t = blockIdx.x * 256 + threadIdx.x;
    int n = t >> 4, j = t & 15;
    if (n >= N) return;
    float div = rsqrtf(fmaxf((float)dout[n], 1.f));
    const float* h = h1 + (size_t)n * 16;
    float a = c1[j], b = c2[j];
    #pragma unroll
    for (int k = 0; k < 16; ++k) { float x = h[k]; a += x * M1[k * 16 + j]; b += x * M2[k * 16 + j]; }
    t12b[(size_t)n * 32 + j] = f2bf(a * div);
    t12b[(size_t)n * 32 + 16 + j] = f2bf(b * div);
}

// ---------------- vectorized agg2: 4 lanes/node x 8ch of 32, uint4 gather -> U,V bf16 ----------------
__global__ __launch_bounds__(256) void k_agg2v(const unsigned short* __restrict__ t12b,
                                               const int* __restrict__ sorted_src, const int* __restrict__ row,
                                               const int* __restrict__ din, const float* __restrict__ prm,
                                               unsigned short* __restrict__ Ub, unsigned short* __restrict__ Vb,
                                               int N) {
    int t = blockIdx.x * 256 + threadIdx.x;
    int n = t >> 2, q = t & 3;
    if (n >= N) return;
    float a0 = 0.f, a1 = 0.f, a2 = 0.f, a3 = 0.f, a4 = 0.f, a5 = 0.f, a6 = 0.f, a7 = 0.f;
    int b = row[n], e = row[n + 1];
    for (int i = b; i < e; ++i) {
        int s = sorted_src[i];
        uint4 w = *(const uint4*)(t12b + (size_t)s * 32 + q * 8);
        a0 += lo16(w.x); a1 += hi16(w.x);
        a2 += lo16(w.y); a3 += hi16(w.y);
        a4 += lo16(w.z); a5 += hi16(w.z);
        a6 += lo16(w.w); a7 += hi16(w.w);
    }
    float div = rsqrtf(fmaxf((float)din[n], 1.f));
    const float* cb = prm + ((q < 2) ? P_CU : P_CV) + (q & 1) * 8;
    uint4 ov;
    ov.x = pack2(a0 * div + cb[0], a1 * div + cb[1]);
    ov.y = pack2(a2 * div + cb[2], a3 * div + cb[3]);
    ov.z = pack2(a4 * div + cb[4], a5 * div + cb[5]);
    ov.w = pack2(a6 * div + cb[6], a7 * div + cb[7]);
    unsigned short* dstp = ((q < 2) ? Ub : Vb) + (size_t)n * 16 + (q & 1) * 8;
    *(uint4*)dstp = ov;
}

// ---------------- edge pass 1: wave-local LDS staging + ds_read_b128, 6 waves/SIMD ----------------
// Round-19 structure (proven 134us @ 4 waves/SIMD). Occupancy raised to 6 waves/SIMD:
// VGPR budget ~85 > the kernel's natural ~48, so no spill (round-21's bound of 8 forced
// VGPR=32 and spilled wcol -> +73MB scratch traffic, 227us).
__global__ __launch_bounds__(256, 6) void k_edge1(const float* __restrict__ ef, const int* __restrict__ src,
                                                  const int* __restrict__ dst, const float* __restrict__ Wp1,
                                                  const float* __restrict__ bp1,
                                                  const unsigned short* __restrict__ Ub,
                                                  const unsigned short* __restrict__ Vb,
                                                  unsigned short* __restrict__ z0h,
                                                  float* __restrict__ statsp, int E) {
    __shared__ float red[32];
    __shared__ __align__(16) float efs[4][4][36];   // [wave][edge][padded row]
    if (threadIdx.x < 32) red[threadIdx.x] = 0.f;
    __syncthreads();

    int l = threadIdx.x & 63;
    int w = threadIdx.x >> 6;
    int g = l >> 4, j = l & 15;

    float wcol[32];
    #pragma unroll
    for (int k = 0; k < 32; ++k) wcol[k] = Wp1[k * 16 + j];
    float bj = bp1[j];

    int wv = (blockIdx.x * 256 + threadIdx.x) >> 6;
    int nW = (gridDim.x * 256) >> 6;
    float sum = 0.f, sq = 0.f;

    #pragma unroll 1
    for (int base = wv * 4; base < E; base += nW * 4) {
        int e = base + g;
        float2 v = make_float2(0.f, 0.f);
        if (e < E) v = ((const float2*)(ef + (size_t)e * FE))[j];
        *(float2*)&efs[w][g][2 * j] = v;           // ds_write_b64, 2-way bank alias (free)
        if (e < E) {
            int s = src[e], d = dst[e];
            float z = bj + bf2f(Ub[s * 16 + j]) + bf2f(Vb[d * 16 + j]);
            #pragma unroll
            for (int q = 0; q < 8; ++q) {
                float4 x = *(const float4*)&efs[w][g][4 * q];   // ds_read_b128 broadcast
                z += x.x * wcol[4 * q + 0] + x.y * wcol[4 * q + 1]
                   + x.z * wcol[4 * q + 2] + x.w * wcol[4 * q + 3];
            }
            z0h[(size_t)e * 16 + j] = f2bf(z);
            sum += z; sq += z * z;
        }
    }

    sum += __shfl_xor(sum, 16, 64); sq += __shfl_xor(sq, 16, 64);
    sum += __shfl_xor(sum, 32, 64); sq += __shfl_xor(sq, 32, 64);
    if (l < 16) { atomicAdd(&red[j], sum); atomicAdd(&red[16 + j], sq); }
    __syncthreads();
    if (threadIdx.x < 16) {
        atomicAdd(&statsp[threadIdx.x], red[threadIdx.x]);
        atomicAdd(&statsp[16 + threadIdx.x], red[16 + threadIdx.x]);
    }
}

// ---------------- fold BN2 into Wp2 ----------------
__global__ __launch_bounds__(128) void k_fold2(const float* __restrict__ stp, const float* __restrict__ gp,
                                               const float* __restrict__ bep, const float* __restrict__ Wp2,
                                               const float* __restrict__ bp2, float* __restrict__ prm, int E) {
    __shared__ float sc[16], sh[16];
    int t = threadIdx.x;
    if (t < 16) {
        float mu = stp[t] / (float)E;
        float var = stp[16 + t] / (float)E - mu * mu;
        float s = gp[t] * rsqrtf(var + EPS);
        sc[t] = s;
        sh[t] = bep[t] - mu * s;
    }
    __syncthreads();
    if (t < 128) { int j = t >> 3, k = t & 7; prm[P_WF + t] = sc[j] * Wp2[j * 8 + k]; }
    if (t < 8) {
        float a = bp2[t];
        #pragma unroll
        for (int j = 0; j < 16; ++j) a += sh[j] * Wp2[j * 8 + t];
        prm[P_BO + t] = a;
    }
}

// ---------------- logits + log_softmax ----------------
__device__ __forceinline__ void logits_out(int e, const float* z, const float* wf, const float* bo,
                                           float* __restrict__ out) {
    float l[8];
    #pragma unroll
    for (int k = 0; k < 8; ++k) l[k] = bo[k];
    #pragma unroll
    for (int j = 0; j < 16; ++j) {
        float x = z[j];
        #pragma unroll
        for (int k = 0; k < 8; ++k) l[k] += x * wf[j * 8 + k];
    }
    float m = l[0];
    #pragma unroll
    for (int k = 1; k < 8; ++k) m = fmaxf(m, l[k]);
    float s = 0.f;
    #pragma unroll
    for (int k = 0; k < 8; ++k) s += expf(l[k] - m);
    float r = m + logf(s);
    float4* op = (float4*)(out + (size_t)e * 8);
    op[0] = make_float4(l[0] - r, l[1] - r, l[2] - r, l[3] - r);
    op[1] = make_float4(l[4] - r, l[5] - r, l[6] - r, l[7] - r);
}

// ---------------- edge pass 2 (read bf16 z0) ----------------
__global__ __launch_bounds__(256) void k_edge2(const unsigned int* __restrict__ z0b,
                                               const float* __restrict__ prm,
                                               float* __restrict__ out, int E) {
    __shared__ float wf[128], bo[8];
    if (threadIdx.x < 128) wf[threadIdx.x] = prm[P_WF + threadIdx.x];
    if (threadIdx.x < 8) bo[threadIdx.x] = prm[P_BO + threadIdx.x];
    __syncthreads();
    int e = blockIdx.x * 256 + threadIdx.x;
    if (e >= E) return;
    const uint4* zp = (const uint4*)(z0b + (size_t)e * 8);
    uint4 a0 = zp[0], a1 = zp[1];
    unsigned int w[8] = {a0.x, a0.y, a0.z, a0.w, a1.x, a1.y, a1.z, a1.w};
    float z[16];
    #pragma unroll
    for (int q = 0; q < 8; ++q) {
        z[2 * q]     = __uint_as_float(w[q] << 16);
        z[2 * q + 1] = __uint_as_float(w[q] & 0xffff0000u);
    }
    logits_out(e, z, wf, bo, out);
}

// ---------------- fallback (ws too small): LDS-staged edge1 stats-only + recompute pass 2 ----------------
__global__ __launch_bounds__(256, 6) void k_edge1_stats(const float* __restrict__ ef, const int* __restrict__ src,
                                                        const int* __restrict__ dst, const float* __restrict__ Wp1,
                                                        const float* __restrict__ bp1,
                                                        const unsigned short* __restrict__ Ub,
                                                        const unsigned short* __restrict__ Vb,
                                                        float* __restrict__ statsp, int E) {
    __shared__ float red[32];
    __shared__ __align__(16) float efs[4][4][36];
    if (threadIdx.x < 32) red[threadIdx.x] = 0.f;
    __syncthreads();
    int l = threadIdx.x & 63;
    int w = threadIdx.x >> 6;
    int g = l >> 4, j = l & 15;
    float wcol[32];
    #pragma unroll
    for (int k = 0; k < 32; ++k) wcol[k] = Wp1[k * 16 + j];
    float bj = bp1[j];
    int wv = (blockIdx.x * 256 + threadIdx.x) >> 6;
    int nW = (gridDim.x * 256) >> 6;
    float sum = 0.f, sq = 0.f;
    #pragma unroll 1
    for (int base = wv * 4; base < E; base += nW * 4) {
        int e = base + g;
        float2 v = make_float2(0.f, 0.f);
        if (e < E) v = ((const float2*)(ef + (size_t)e * FE))[j];
        *(float2*)&efs[w][g][2 * j] = v;
        if (e < E) {
            int s = src[e], d = dst[e];
            float z = bj + bf2f(Ub[s * 16 + j]) + bf2f(Vb[d * 16 + j]);
            #pragma unroll
            for (int q = 0; q < 8; ++q) {
                float4 x = *(const float4*)&efs[w][g][4 * q];
                z += x.x * wcol[4 * q + 0] + x.y * wcol[4 * q + 1]
                   + x.z * wcol[4 * q + 2] + x.w * wcol[4 * q + 3];
            }
            sum += z; sq += z * z;
        }
    }
    sum += __shfl_xor(sum, 16, 64); sq += __shfl_xor(sq, 16, 64);
    sum += __shfl_xor(sum, 32, 64); sq += __shfl_xor(sq, 32, 64);
    if (l < 16) { atomicAdd(&red[j], sum); atomicAdd(&red[16 + j], sq); }
    __syncthreads();
    if (threadIdx.x < 16) {
        atomicAdd(&statsp[threadIdx.x], red[threadIdx.x]);
        atomicAdd(&statsp[16 + threadIdx.x], red[16 + threadIdx.x]);
    }
}

__global__ __launch_bounds__(256, 2) void k_edge2_rc(const float* __restrict__ ef, const int* __restrict__ src,
                                                     const int* __restrict__ dst, const float* __restrict__ Wp1,
                                                     const float* __restrict__ bp1,
                                                     const unsigned short* __restrict__ Ub,
                                                     const unsigned short* __restrict__ Vb,
                                                     const float* __restrict__ prm,
                                                     float* __restrict__ out, int E) {
    __shared__ float wa[FE * 16];
    __shared__ float bb[16];
    __shared__ float wf[128], bo[8];
    for (int i = threadIdx.x; i < FE * 16; i += 256) wa[i] = Wp1[i];
    if (threadIdx.x < 16) bb[threadIdx.x] = bp1[threadIdx.x];
    if (threadIdx.x < 128) wf[threadIdx.x] = prm[P_WF + threadIdx.x];
    if (threadIdx.x < 8) bo[threadIdx.x] = prm[P_BO + threadIdx.x];
    __syncthreads();
    int e = blockIdx.x * 256 + threadIdx.x;
    if (e >= E) return;
    float z[16];
    {
        int s = src[e], d = dst[e];
        const uint4* up = (const uint4*)(Ub + (size_t)s * 16);
        const uint4* vp = (const uint4*)(Vb + (size_t)d * 16);
        #pragma unroll
        for (int h = 0; h < 2; ++h) {
            uint4 ua = up[h], va = vp[h];
            unsigned int uu[4] = {ua.x, ua.y, ua.z, ua.w};
            unsigned int vv[4] = {va.x, va.y, va.z, va.w};
            #pragma unroll
            for (int q = 0; q < 4; ++q) {
                int jj = h * 8 + 2 * q;
                z[jj]     = bb[jj]     + __uint_as_float(uu[q] << 16)          + __uint_as_float(vv[q] << 16);
                z[jj + 1] = bb[jj + 1] + __uint_as_float(uu[q] & 0xffff0000u) + __uint_as_float(vv[q] & 0xffff0000u);
            }
        }
    }
    const float4* ep = (const float4*)(ef + (size_t)e * FE);
    #pragma unroll
    for (int q = 0; q < 8; ++q) {
        float4 x4 = ep[q];
        float xs[4] = {x4.x, x4.y, x4.z, x4.w};
        #pragma unroll
        for (int kk = 0; kk < 4; ++kk) {
            float x = xs[kk];
            #pragma unroll
            for (int jj = 0; jj < 16; ++jj) z[jj] += x * wa[(q * 4 + kk) * 16 + jj];
        }
    }
    logits_out(e, z, wf, bo, out);
}

extern "C" void kernel_launch(void* const* d_in, const int* in_sizes, int n_in,
                              void* d_out, int out_size, void* d_ws, size_t ws_size,
                              hipStream_t stream) {
    const float* n_feats = (const float*)d_in[0];
    const float* e_feats = (const float*)d_in[1];
    const int*   src     = (const int*)d_in[2];
    const int*   dst     = (const int*)d_in[3];
    const float* W1      = (const float*)d_in[4];
    const float* b1      = (const float*)d_in[5];
    const float* g1      = (const float*)d_in[6];
    const float* be1     = (const float*)d_in[7];
    const float* W2      = (const float*)d_in[8];
    const float* b2      = (const float*)d_in[9];
    const float* Wp1     = (const float*)d_in[10];
    const float* bp1     = (const float*)d_in[11];
    const float* gp      = (const float*)d_in[12];
    const float* bep     = (const float*)d_in[13];
    const float* Wp2     = (const float*)d_in[14];
    const float* bp2     = (const float*)d_in[15];
    float* out = (float*)d_out;

    int N = in_sizes[0] / F_IN;
    int E = in_sizes[2];
    float* ws = (float*)d_ws;
    int NB = (N + 255) / 256;
    int BKT = (N + 255) >> 8;   // 256 nodes per bucket (== NB)

    size_t off = 0;
    auto take = [&](size_t n) { size_t r = off; off += (n + 15) & ~(size_t)15; return r; };
    size_t o_dout_i = take((size_t)N);
    size_t o_din_i  = take((size_t)N);
    size_t o_st1    = take(32);
    size_t o_stp    = take(32);
    size_t zeroUnits = off;
    size_t o_row    = take((size_t)N + 1);
    size_t o_cursor = take((size_t)N);
    size_t o_bsum   = take((size_t)NB);
    size_t o_bcur   = take(256);
    size_t o_sorted = take((size_t)E);
    size_t o_prm    = take(1024);
    size_t o_s1b    = take((size_t)8 * N);
    size_t o_h1     = take((size_t)16 * N);
    size_t o_t12b   = take((size_t)16 * N);
    size_t o_Ub     = take((size_t)8 * N);
    size_t o_Vb     = take((size_t)8 * N);
    size_t o_binned = take((size_t)2 * E);
    size_t o_z0b    = off;
    bool store_z = ws_size >= (off + (size_t)8 * E) * 4;
    bool use_bin = (BKT <= 256) && (ws_size >= off * 4);

    hipMemsetAsync(ws, 0, zeroUnits * 4, stream);

    int* dout_i = (int*)(ws + o_dout_i);
    int* din_i  = (int*)(ws + o_din_i);
    int* rowp   = (int*)(ws + o_row);
    int* curp   = (int*)(ws + o_cursor);
    int* bsump  = (int*)(ws + o_bsum);
    int* bcurp  = (int*)(ws + o_bcur);
    int* sortedp = (int*)(ws + o_sorted);
    uint2* binnedp = (uint2*)(ws + o_binned);
    unsigned short* s1b  = (unsigned short*)(ws + o_s1b);
    unsigned short* t12b = (unsigned short*)(ws + o_t12b);
    unsigned short* Ub   = (unsigned short*)(ws + o_Ub);
    unsigned short* Vb   = (unsigned short*)(ws + o_Vb);
    unsigned short* z0h  = (unsigned short*)(ws + o_z0b);
    unsigned int* z0b    = (unsigned int*)(ws + o_z0b);

    int bE = (E + 255) / 256;
    int bN16 = (N * 16 + 255) / 256;
    int bAgg = (N * 4 + 255) / 256;

    k_deg<<<bE, 256, 0, stream>>>(src, dst, dout_i, din_i, E);
    k_scanA<<<NB, 256, 0, stream>>>(din_i, bsump, N);
    k_scanB<<<1, 256, 0, stream>>>(bsump, NB, rowp + N, bcurp);
    k_scanC<<<NB, 256, 0, stream>>>(din_i, bsump, rowp, curp, N);
    if (use_bin) {
        k_bin<<<256, 256, 0, stream>>>(src, dst, bcurp, binnedp, E, 256);
        k_scat<<<BKT, 256, 0, stream>>>(binnedp, rowp, sortedp, N);
    } else {
        k_sortedges<<<bE, 256, 0, stream>>>(src, dst, curp, sortedp, E);
    }
    k_s1<<<bN16, 256, 0, stream>>>(n_feats, W1, dout_i, s1b, N);
    k_agg1v<<<bAgg, 256, 0, stream>>>(s1b, sortedp, rowp, din_i, b1, ws + o_h1, ws + o_st1, N);
    k_fold<<<1, 256, 0, stream>>>(ws + o_st1, g1, be1, W2, b2, Wp1, ws + o_prm, N);
    k_t<<<bN16, 256, 0, stream>>>(ws + o_h1, dout_i, ws + o_prm, t12b, N);
    k_agg2v<<<bAgg, 256, 0, stream>>>(t12b, sortedp, rowp, din_i, ws + o_prm, Ub, Vb, N);

    if (store_z) {
        // 6 waves/SIMD: 1536 blocks = 6 blocks/CU on 256 CUs
        k_edge1<<<1536, 256, 0, stream>>>(e_feats, src, dst, Wp1, bp1, Ub, Vb, z0h, ws + o_stp, E);
        k_fold2<<<1, 128, 0, stream>>>(ws + o_stp, gp, bep, Wp2, bp2, ws + o_prm, E);
        k_edge2<<<bE, 256, 0, stream>>>(z0b, ws + o_prm, out, E);
    } else {
        k_edge1_stats<<<1536, 256, 0, stream>>>(e_feats, src, dst, Wp1, bp1, Ub, Vb, ws + o_stp, E);
        k_fold2<<<1, 128, 0, stream>>>(ws + o_stp, gp, bep, Wp2, bp2, ws + o_prm, E);
        k_edge2_rc<<<bE, 256, 0, stream>>>(e_feats, src, dst, Wp1, bp1, Ub, Vb, ws + o_prm, out, E);
    }
}

// Round 23
// 419.738 us; speedup vs baseline: 1.1882x; 1.0555x over previous
//
#include <hip/hip_runtime.h>
#include <hip/hip_bf16.h>
#include <math.h>
#include <stddef.h>

#define EPS 1e-5f
#define F_IN 128
#define FE 32

// prm layout (float offsets)
#define P_M1 0
#define P_M2 256
#define P_C1 512
#define P_C2 528
#define P_CU 544
#define P_CV 560
#define P_WF 576
#define P_BO 704

// ---- bf16 helpers ----
__device__ __forceinline__ float bf2f(unsigned short u) {
    return __uint_as_float(((unsigned int)u) << 16);
}
__device__ __forceinline__ unsigned short f2bf(float f) {
    unsigned int u = __float_as_uint(f);
    u = (u + 0x7fffu + ((u >> 16) & 1u)) >> 16;
    return (unsigned short)u;
}
__device__ __forceinline__ unsigned int pack2(float a, float b) {
    return (unsigned int)f2bf(a) | ((unsigned int)f2bf(b) << 16);
}
__device__ __forceinline__ float lo16(unsigned int w) { return __uint_as_float(w << 16); }
__device__ __forceinline__ float hi16(unsigned int w) { return __uint_as_float(w & 0xffff0000u); }

// ---------------- degree (int counts) ----------------
__global__ __launch_bounds__(256) void k_deg(const int* __restrict__ src, const int* __restrict__ dst,
                                             int* __restrict__ dout, int* __restrict__ din, int E) {
    int e = blockIdx.x * 256 + threadIdx.x;
    if (e < E) {
        atomicAdd(&dout[src[e]], 1);
        atomicAdd(&din[dst[e]], 1);
    }
}

// ---------------- parallel scan phase A: per-block sums (coalesced) ----------------
__global__ __launch_bounds__(256) void k_scanA(const int* __restrict__ deg, int* __restrict__ bsum, int N) {
    int i = blockIdx.x * 256 + threadIdx.x;
    int v = (i < N) ? deg[i] : 0;
    #pragma unroll
    for (int m = 1; m < 64; m <<= 1) v += __shfl_xor(v, m, 64);
    __shared__ int red[4];
    if ((threadIdx.x & 63) == 0) red[threadIdx.x >> 6] = v;
    __syncthreads();
    if (threadIdx.x == 0) bsum[blockIdx.x] = red[0] + red[1] + red[2] + red[3];
}

// ---------------- phase B: 1-block exclusive scan of block sums; also emits bucket cursors ----------------
__global__ __launch_bounds__(256) void k_scanB(int* __restrict__ bsum, int NB, int* __restrict__ rowN,
                                               int* __restrict__ bcur) {
    __shared__ int s[256];
    int per = (NB + 255) >> 8;
    int start = threadIdx.x * per;
    int end = start + per; if (end > NB) end = NB; if (start > NB) start = NB;
    int sum = 0;
    for (int i = start; i < end; ++i) sum += bsum[i];
    s[threadIdx.x] = sum;
    __syncthreads();
    for (int off = 1; off < 256; off <<= 1) {
        int t = (threadIdx.x >= off) ? s[threadIdx.x - off] : 0;
        __syncthreads();
        s[threadIdx.x] += t;
        __syncthreads();
    }
    int run = (threadIdx.x == 0) ? 0 : s[threadIdx.x - 1];
    for (int i = start; i < end; ++i) {
        int v = bsum[i];
        bsum[i] = run;
        bcur[i] = run;   // bucket b starts at exclusive prefix of its 256-node block
        run += v;
    }
    if (threadIdx.x == 255) rowN[0] = s[255];
}

// ---------------- phase C: per-block LDS scan + block offset -> row, cursor ----------------
__global__ __launch_bounds__(256) void k_scanC(const int* __restrict__ deg, const int* __restrict__ boff,
                                               int* __restrict__ row, int* __restrict__ cursor, int N) {
    __shared__ int s[256];
    int i = blockIdx.x * 256 + threadIdx.x;
    int v = (i < N) ? deg[i] : 0;
    s[threadIdx.x] = v;
    __syncthreads();
    for (int off = 1; off < 256; off <<= 1) {
        int t = (threadIdx.x >= off) ? s[threadIdx.x - off] : 0;
        __syncthreads();
        s[threadIdx.x] += t;
        __syncthreads();
    }
    int r = boff[blockIdx.x] + s[threadIdx.x] - v;
    if (i < N) { row[i] = r; cursor[i] = r; }
}

// ---------------- bin pass: group (src,dst) pairs by dst-bucket, coalesced writes ----------------
__global__ __launch_bounds__(256) void k_bin(const int* __restrict__ src, const int* __restrict__ dst,
                                             int* __restrict__ bcur, uint2* __restrict__ binned,
                                             int E, int nBlocks) {
    __shared__ int hist[256], base[256], offs[256];
    int chunk = (E + nBlocks - 1) / nBlocks;
    int start = blockIdx.x * chunk;
    int end = start + chunk; if (end > E) end = E;
    hist[threadIdx.x] = 0; offs[threadIdx.x] = 0;
    __syncthreads();
    for (int i = start + threadIdx.x; i < end; i += 256)
        atomicAdd(&hist[dst[i] >> 8], 1);
    __syncthreads();
    int h = hist[threadIdx.x];
    base[threadIdx.x] = h ? atomicAdd(&bcur[threadIdx.x], h) : 0;
    __syncthreads();
    for (int i = start + threadIdx.x; i < end; i += 256) {
        int d = dst[i], b = d >> 8;
        int p = base[b] + atomicAdd(&offs[b], 1);
        binned[p] = make_uint2((unsigned int)src[i], (unsigned int)d);
    }
}

// ---------------- scatter pass: one WG per bucket, LDS cursors, L2-local writes ----------------
__global__ __launch_bounds__(256) void k_scat(const uint2* __restrict__ binned, const int* __restrict__ row,
                                              int* __restrict__ sorted_src, int N) {
    __shared__ int cur[256];
    int nb = blockIdx.x << 8;
    int hi = nb + 256; if (hi > N) hi = N;
    if (nb + threadIdx.x < N) cur[threadIdx.x] = row[nb + threadIdx.x];
    __syncthreads();
    int eStart = row[nb], eEnd = row[hi];
    for (int i = eStart + threadIdx.x; i < eEnd; i += 256) {
        uint2 p = binned[i];
        int pos = atomicAdd(&cur[(int)p.y - nb], 1);
        sorted_src[pos] = (int)p.x;
    }
}

// ---------------- counting-sort fallback (no-bin path) ----------------
__global__ __launch_bounds__(256) void k_sortedges(const int* __restrict__ src, const int* __restrict__ dst,
                                                   int* __restrict__ cursor, int* __restrict__ sorted_src, int E) {
    int e = blockIdx.x * 256 + threadIdx.x;
    if (e < E) {
        int p = atomicAdd(&cursor[dst[e]], 1);
        sorted_src[p] = src[e];
    }
}

// ---------------- s1 = (n_feats @ W1) * rsqrt(deg_out)  (bf16 out) ----------------
__global__ __launch_bounds__(256) void k_s1(const float* __restrict__ x, const float* __restrict__ W1,
                                            const int* __restrict__ dout, unsigned short* __restrict__ s1b, int N) {
    __shared__ float w[F_IN * 16];
    for (int i = threadIdx.x; i < F_IN * 16; i += 256) w[i] = W1[i];
    __syncthreads();
    int t = blockIdx.x * 256 + threadIdx.x;
    int n = t >> 4, j = t & 15;
    if (n >= N) return;
    const float* row = x + (size_t)n * F_IN;
    float acc = 0.f;
    #pragma unroll 8
    for (int k = 0; k < F_IN; ++k) acc += row[k] * w[k * 16 + j];
    s1b[(size_t)n * 16 + j] = f2bf(acc * rsqrtf(fmaxf((float)dout[n], 1.0f)));
}

// ---------------- vectorized agg1: 4 lanes/node x 4ch, uint2 gather; relu + BN1 stats ----------------
__global__ __launch_bounds__(256) void k_agg1v(const unsigned short* __restrict__ s1b,
                                               const int* __restrict__ sorted_src, const int* __restrict__ row,
                                               const int* __restrict__ din, const float* __restrict__ b1,
                                               float* __restrict__ h1, float* __restrict__ st1, int N) {
    __shared__ float lsum[16], lsq[16];
    if (threadIdx.x < 16) { lsum[threadIdx.x] = 0.f; lsq[threadIdx.x] = 0.f; }
    __syncthreads();
    int t = blockIdx.x * 256 + threadIdx.x;
    int n = t >> 2, q = t & 3;
    float v0 = 0.f, v1 = 0.f, v2 = 0.f, v3 = 0.f;
    if (n < N) {
        float a0 = 0.f, a1 = 0.f, a2 = 0.f, a3 = 0.f;
        int b = row[n], e = row[n + 1];
        for (int i = b; i < e; ++i) {
            int s = sorted_src[i];
            uint2 w = *(const uint2*)(s1b + (size_t)s * 16 + q * 4);
            a0 += lo16(w.x); a1 += hi16(w.x);
            a2 += lo16(w.y); a3 += hi16(w.y);
        }
        float div = rsqrtf(fmaxf((float)din[n], 1.f));
        v0 = fmaxf(a0 * div + b1[q * 4 + 0], 0.f);
        v1 = fmaxf(a1 * div + b1[q * 4 + 1], 0.f);
        v2 = fmaxf(a2 * div + b1[q * 4 + 2], 0.f);
        v3 = fmaxf(a3 * div + b1[q * 4 + 3], 0.f);
        *(float4*)(h1 + (size_t)n * 16 + q * 4) = make_float4(v0, v1, v2, v3);
    }
    float s0 = v0, s1 = v1, s2 = v2, s3 = v3;
    float q0 = v0 * v0, q1 = v1 * v1, q2 = v2 * v2, q3 = v3 * v3;
    #pragma unroll
    for (int m = 4; m < 64; m <<= 1) {
        s0 += __shfl_xor(s0, m, 64); q0 += __shfl_xor(q0, m, 64);
        s1 += __shfl_xor(s1, m, 64); q1 += __shfl_xor(q1, m, 64);
        s2 += __shfl_xor(s2, m, 64); q2 += __shfl_xor(q2, m, 64);
        s3 += __shfl_xor(s3, m, 64); q3 += __shfl_xor(q3, m, 64);
    }
    if ((threadIdx.x & 63) < 4) {
        int j = (threadIdx.x & 3) * 4;
        atomicAdd(&lsum[j + 0], s0); atomicAdd(&lsq[j + 0], q0);
        atomicAdd(&lsum[j + 1], s1); atomicAdd(&lsq[j + 1], q1);
        atomicAdd(&lsum[j + 2], s2); atomicAdd(&lsq[j + 2], q2);
        atomicAdd(&lsum[j + 3], s3); atomicAdd(&lsq[j + 3], q3);
    }
    __syncthreads();
    if (threadIdx.x < 16) {
        atomicAdd(&st1[threadIdx.x], lsum[threadIdx.x]);
        atomicAdd(&st1[16 + threadIdx.x], lsq[threadIdx.x]);
    }
}

// ---------------- fold BN1 + W2 + Wp1 slices into M1,M2 + vectors ----------------
__global__ __launch_bounds__(256) void k_fold(const float* __restrict__ st, const float* __restrict__ g1,
                                              const float* __restrict__ be1, const float* __restrict__ W2,
                                              const float* __restrict__ b2, const float* __restrict__ Wp1,
                                              float* __restrict__ prm, int N) {
    __shared__ float scale[16], shift[16], d2[64];
    int t = threadIdx.x;
    if (t < 16) {
        float mu = st[t] / (float)N;
        float var = st[16 + t] / (float)N - mu * mu;
        float sc = g1[t] * rsqrtf(var + EPS);
        scale[t] = sc;
        shift[t] = be1[t] - mu * sc;
    }
    __syncthreads();
    if (t < 64) {
        float acc = 0.f;
        #pragma unroll
        for (int j = 0; j < 16; ++j) acc += shift[j] * W2[j * 64 + t];
        d2[t] = acc;
    }
    __syncthreads();
    {
        int j1 = t >> 4, j2 = t & 15;
        float m1 = 0.f, m2 = 0.f;
        float sc = scale[j1];
        for (int c = 0; c < 64; ++c) {
            float w = sc * W2[j1 * 64 + c];
            m1 += w * Wp1[(32 + c) * 16 + j2];
            m2 += w * Wp1[(96 + c) * 16 + j2];
        }
        prm[P_M1 + j1 * 16 + j2] = m1;
        prm[P_M2 + j1 * 16 + j2] = m2;
    }
    if (t < 16) {
        float a = 0.f, b = 0.f, u = 0.f, v = 0.f;
        for (int c = 0; c < 64; ++c) {
            float wb = Wp1[(32 + c) * 16 + t], wc = Wp1[(96 + c) * 16 + t];
            a += d2[c] * wb; b += d2[c] * wc;
            u += b2[c] * wb; v += b2[c] * wc;
        }
        prm[P_C1 + t] = a; prm[P_C2 + t] = b;
        prm[P_CU + t] = u; prm[P_CV + t] = v;
    }
}

// ---------------- t12 = rsqrt(deg_out)*(h1@M1+c1) || (h1@M2+c2)  (interleaved 32 bf16/node) ----------------
__global__ __launch_bounds__(256) void k_t(const float* __restrict__ h1, const int* __restrict__ dout,
                                           const float* __restrict__ prm, unsigned short* __restrict__ t12b, int N) {
    __shared__ float M1[256], M2[256], c1[16], c2[16];
    for (int i = threadIdx.x; i < 256; i += 256) { M1[i] = prm[P_M1 + i]; M2[i] = prm[P_M2 + i]; }
    if (threadIdx.x < 16) { c1[threadIdx.x] = prm[P_C1 + threadIdx.x]; c2[threadIdx.x] = prm[P_C2 + threadIdx.x]; }
    __syncthreads();
    int t = blockIdx.x * 256 + threadIdx.x;
    int n = t >> 4, j = t & 15;
    if (n >= N) return;
    float div = rsqrtf(fmaxf((float)dout[n], 1.f));
    const float* h = h1 + (size_t)n * 16;
    float a = c1[j], b = c2[j];
    #pragma unroll
    for (int k = 0; k < 16; ++k) { float x = h[k]; a += x * M1[k * 16 + j]; b += x * M2[k * 16 + j]; }
    t12b[(size_t)n * 32 + j] = f2bf(a * div);
    t12b[(size_t)n * 32 + 16 + j] = f2bf(b * div);
}

// ---------------- vectorized agg2: 4 lanes/node x 8ch of 32, uint4 gather -> U,V bf16 ----------------
__global__ __launch_bounds__(256) void k_agg2v(const unsigned short* __restrict__ t12b,
                                               const int* __restrict__ sorted_src, const int* __restrict__ row,
                                               const int* __restrict__ din, const float* __restrict__ prm,
                                               unsigned short* __restrict__ Ub, unsigned short* __restrict__ Vb,
                                               int N) {
    int t = blockIdx.x * 256 + threadIdx.x;
    int n = t >> 2, q = t & 3;
    if (n >= N) return;
    float a0 = 0.f, a1 = 0.f, a2 = 0.f, a3 = 0.f, a4 = 0.f, a5 = 0.f, a6 = 0.f, a7 = 0.f;
    int b = row[n], e = row[n + 1];
    for (int i = b; i < e; ++i) {
        int s = sorted_src[i];
        uint4 w = *(const uint4*)(t12b + (size_t)s * 32 + q * 8);
        a0 += lo16(w.x); a1 += hi16(w.x);
        a2 += lo16(w.y); a3 += hi16(w.y);
        a4 += lo16(w.z); a5 += hi16(w.z);
        a6 += lo16(w.w); a7 += hi16(w.w);
    }
    float div = rsqrtf(fmaxf((float)din[n], 1.f));
    const float* cb = prm + ((q < 2) ? P_CU : P_CV) + (q & 1) * 8;
    uint4 ov;
    ov.x = pack2(a0 * div + cb[0], a1 * div + cb[1]);
    ov.y = pack2(a2 * div + cb[2], a3 * div + cb[3]);
    ov.z = pack2(a4 * div + cb[4], a5 * div + cb[5]);
    ov.w = pack2(a6 * div + cb[6], a7 * div + cb[7]);
    unsigned short* dstp = ((q < 2) ? Ub : Vb) + (size_t)n * 16 + (q & 1) * 8;
    *(uint4*)dstp = ov;
}

// ---------------- edge pass 1: wave-local LDS staging + ds_read_b128, natural regalloc ----------------
// Round-19 structure (proven 134us). No min-wave constraint: natural VGPR ~48 allows up to
// 8 waves/SIMD by hardware limit (512/48>8) with no forced spill (rounds 21/22 showed forcing
// min-waves shrinks VGPR below the natural 48 and spills). Grid 4096 = 8 blocks/CU available.
__global__ __launch_bounds__(256) void k_edge1(const float* __restrict__ ef, const int* __restrict__ src,
                                               const int* __restrict__ dst, const float* __restrict__ Wp1,
                                               const float* __restrict__ bp1,
                                               const unsigned short* __restrict__ Ub,
                                               const unsigned short* __restrict__ Vb,
                                               unsigned short* __restrict__ z0h,
                                               float* __restrict__ statsp, int E) {
    __shared__ float red[32];
    __shared__ __align__(16) float efs[4][4][36];   // [wave][edge][padded row]
    if (threadIdx.x < 32) red[threadIdx.x] = 0.f;
    __syncthreads();

    int l = threadIdx.x & 63;
    int w = threadIdx.x >> 6;
    int g = l >> 4, j = l & 15;

    float wcol[32];
    #pragma unroll
    for (int k = 0; k < 32; ++k) wcol[k] = Wp1[k * 16 + j];
    float bj = bp1[j];

    int wv = (blockIdx.x * 256 + threadIdx.x) >> 6;
    int nW = (gridDim.x * 256) >> 6;
    float sum = 0.f, sq = 0.f;

    #pragma unroll 1
    for (int base = wv * 4; base < E; base += nW * 4) {
        int e = base + g;
        float2 v = make_float2(0.f, 0.f);
        if (e < E) v = ((const float2*)(ef + (size_t)e * FE))[j];
        *(float2*)&efs[w][g][2 * j] = v;           // ds_write_b64, 2-way bank alias (free)
        if (e < E) {
            int s = src[e], d = dst[e];
            float z = bj + bf2f(Ub[s * 16 + j]) + bf2f(Vb[d * 16 + j]);
            #pragma unroll
            for (int q = 0; q < 8; ++q) {
                float4 x = *(const float4*)&efs[w][g][4 * q];   // ds_read_b128 broadcast
                z += x.x * wcol[4 * q + 0] + x.y * wcol[4 * q + 1]
                   + x.z * wcol[4 * q + 2] + x.w * wcol[4 * q + 3];
            }
            z0h[(size_t)e * 16 + j] = f2bf(z);
            sum += z; sq += z * z;
        }
    }

    sum += __shfl_xor(sum, 16, 64); sq += __shfl_xor(sq, 16, 64);
    sum += __shfl_xor(sum, 32, 64); sq += __shfl_xor(sq, 32, 64);
    if (l < 16) { atomicAdd(&red[j], sum); atomicAdd(&red[16 + j], sq); }
    __syncthreads();
    if (threadIdx.x < 16) {
        atomicAdd(&statsp[threadIdx.x], red[threadIdx.x]);
        atomicAdd(&statsp[16 + threadIdx.x], red[16 + threadIdx.x]);
    }
}

// ---------------- fold BN2 into Wp2 ----------------
__global__ __launch_bounds__(128) void k_fold2(const float* __restrict__ stp, const float* __restrict__ gp,
                                               const float* __restrict__ bep, const float* __restrict__ Wp2,
                                               const float* __restrict__ bp2, float* __restrict__ prm, int E) {
    __shared__ float sc[16], sh[16];
    int t = threadIdx.x;
    if (t < 16) {
        float mu = stp[t] / (float)E;
        float var = stp[16 + t] / (float)E - mu * mu;
        float s = gp[t] * rsqrtf(var + EPS);
        sc[t] = s;
        sh[t] = bep[t] - mu * s;
    }
    __syncthreads();
    if (t < 128) { int j = t >> 3, k = t & 7; prm[P_WF + t] = sc[j] * Wp2[j * 8 + k]; }
    if (t < 8) {
        float a = bp2[t];
        #pragma unroll
        for (int j = 0; j < 16; ++j) a += sh[j] * Wp2[j * 8 + t];
        prm[P_BO + t] = a;
    }
}

// ---------------- logits + log_softmax ----------------
__device__ __forceinline__ void logits_out(int e, const float* z, const float* wf, const float* bo,
                                           float* __restrict__ out) {
    float l[8];
    #pragma unroll
    for (int k = 0; k < 8; ++k) l[k] = bo[k];
    #pragma unroll
    for (int j = 0; j < 16; ++j) {
        float x = z[j];
        #pragma unroll
        for (int k = 0; k < 8; ++k) l[k] += x * wf[j * 8 + k];
    }
    float m = l[0];
    #pragma unroll
    for (int k = 1; k < 8; ++k) m = fmaxf(m, l[k]);
    float s = 0.f;
    #pragma unroll
    for (int k = 0; k < 8; ++k) s += expf(l[k] - m);
    float r = m + logf(s);
    float4* op = (float4*)(out + (size_t)e * 8);
    op[0] = make_float4(l[0] - r, l[1] - r, l[2] - r, l[3] - r);
    op[1] = make_float4(l[4] - r, l[5] - r, l[6] - r, l[7] - r);
}

// ---------------- edge pass 2 (read bf16 z0) ----------------
__global__ __launch_bounds__(256) void k_edge2(const unsigned int* __restrict__ z0b,
                                               const float* __restrict__ prm,
                                               float* __restrict__ out, int E) {
    __shared__ float wf[128], bo[8];
    if (threadIdx.x < 128) wf[threadIdx.x] = prm[P_WF + threadIdx.x];
    if (threadIdx.x < 8) bo[threadIdx.x] = prm[P_BO + threadIdx.x];
    __syncthreads();
    int e = blockIdx.x * 256 + threadIdx.x;
    if (e >= E) return;
    const uint4* zp = (const uint4*)(z0b + (size_t)e * 8);
    uint4 a0 = zp[0], a1 = zp[1];
    unsigned int w[8] = {a0.x, a0.y, a0.z, a0.w, a1.x, a1.y, a1.z, a1.w};
    float z[16];
    #pragma unroll
    for (int q = 0; q < 8; ++q) {
        z[2 * q]     = __uint_as_float(w[q] << 16);
        z[2 * q + 1] = __uint_as_float(w[q] & 0xffff0000u);
    }
    logits_out(e, z, wf, bo, out);
}

// ---------------- fallback (ws too small): LDS-staged edge1 stats-only + recompute pass 2 ----------------
__global__ __launch_bounds__(256) void k_edge1_stats(const float* __restrict__ ef, const int* __restrict__ src,
                                                     const int* __restrict__ dst, const float* __restrict__ Wp1,
                                                     const float* __restrict__ bp1,
                                                     const unsigned short* __restrict__ Ub,
                                                     const unsigned short* __restrict__ Vb,
                                                     float* __restrict__ statsp, int E) {
    __shared__ float red[32];
    __shared__ __align__(16) float efs[4][4][36];
    if (threadIdx.x < 32) red[threadIdx.x] = 0.f;
    __syncthreads();
    int l = threadIdx.x & 63;
    int w = threadIdx.x >> 6;
    int g = l >> 4, j = l & 15;
    float wcol[32];
    #pragma unroll
    for (int k = 0; k < 32; ++k) wcol[k] = Wp1[k * 16 + j];
    float bj = bp1[j];
    int wv = (blockIdx.x * 256 + threadIdx.x) >> 6;
    int nW = (gridDim.x * 256) >> 6;
    float sum = 0.f, sq = 0.f;
    #pragma unroll 1
    for (int base = wv * 4; base < E; base += nW * 4) {
        int e = base + g;
        float2 v = make_float2(0.f, 0.f);
        if (e < E) v = ((const float2*)(ef + (size_t)e * FE))[j];
        *(float2*)&efs[w][g][2 * j] = v;
        if (e < E) {
            int s = src[e], d = dst[e];
            float z = bj + bf2f(Ub[s * 16 + j]) + bf2f(Vb[d * 16 + j]);
            #pragma unroll
            for (int q = 0; q < 8; ++q) {
                float4 x = *(const float4*)&efs[w][g][4 * q];
                z += x.x * wcol[4 * q + 0] + x.y * wcol[4 * q + 1]
                   + x.z * wcol[4 * q + 2] + x.w * wcol[4 * q + 3];
            }
            sum += z; sq += z * z;
        }
    }
    sum += __shfl_xor(sum, 16, 64); sq += __shfl_xor(sq, 16, 64);
    sum += __shfl_xor(sum, 32, 64); sq += __shfl_xor(sq, 32, 64);
    if (l < 16) { atomicAdd(&red[j], sum); atomicAdd(&red[16 + j], sq); }
    __syncthreads();
    if (threadIdx.x < 16) {
        atomicAdd(&statsp[threadIdx.x], red[threadIdx.x]);
        atomicAdd(&statsp[16 + threadIdx.x], red[16 + threadIdx.x]);
    }
}

__global__ __launch_bounds__(256, 2) void k_edge2_rc(const float* __restrict__ ef, const int* __restrict__ src,
                                                     const int* __restrict__ dst, const float* __restrict__ Wp1,
                                                     const float* __restrict__ bp1,
                                                     const unsigned short* __restrict__ Ub,
                                                     const unsigned short* __restrict__ Vb,
                                                     const float* __restrict__ prm,
                                                     float* __restrict__ out, int E) {
    __shared__ float wa[FE * 16];
    __shared__ float bb[16];
    __shared__ float wf[128], bo[8];
    for (int i = threadIdx.x; i < FE * 16; i += 256) wa[i] = Wp1[i];
    if (threadIdx.x < 16) bb[threadIdx.x] = bp1[threadIdx.x];
    if (threadIdx.x < 128) wf[threadIdx.x] = prm[P_WF + threadIdx.x];
    if (threadIdx.x < 8) bo[threadIdx.x] = prm[P_BO + threadIdx.x];
    __syncthreads();
    int e = blockIdx.x * 256 + threadIdx.x;
    if (e >= E) return;
    float z[16];
    {
        int s = src[e], d = dst[e];
        const uint4* up = (const uint4*)(Ub + (size_t)s * 16);
        const uint4* vp = (const uint4*)(Vb + (size_t)d * 16);
        #pragma unroll
        for (int h = 0; h < 2; ++h) {
            uint4 ua = up[h], va = vp[h];
            unsigned int uu[4] = {ua.x, ua.y, ua.z, ua.w};
            unsigned int vv[4] = {va.x, va.y, va.z, va.w};
            #pragma unroll
            for (int q = 0; q < 4; ++q) {
                int jj = h * 8 + 2 * q;
                z[jj]     = bb[jj]     + __uint_as_float(uu[q] << 16)          + __uint_as_float(vv[q] << 16);
                z[jj + 1] = bb[jj + 1] + __uint_as_float(uu[q] & 0xffff0000u) + __uint_as_float(vv[q] & 0xffff0000u);
            }
        }
    }
    const float4* ep = (const float4*)(ef + (size_t)e * FE);
    #pragma unroll
    for (int q = 0; q < 8; ++q) {
        float4 x4 = ep[q];
        float xs[4] = {x4.x, x4.y, x4.z, x4.w};
        #pragma unroll
        for (int kk = 0; kk < 4; ++kk) {
            float x = xs[kk];
            #pragma unroll
            for (int jj = 0; jj < 16; ++jj) z[jj] += x * wa[(q * 4 + kk) * 16 + jj];
        }
    }
    logits_out(e, z, wf, bo, out);
}

extern "C" void kernel_launch(void* const* d_in, const int* in_sizes, int n_in,
                              void* d_out, int out_size, void* d_ws, size_t ws_size,
                              hipStream_t stream) {
    const float* n_feats = (const float*)d_in[0];
    const float* e_feats = (const float*)d_in[1];
    const int*   src     = (const int*)d_in[2];
    const int*   dst     = (const int*)d_in[3];
    const float* W1      = (const float*)d_in[4];
    const float* b1      = (const float*)d_in[5];
    const float* g1      = (const float*)d_in[6];
    const float* be1     = (const float*)d_in[7];
    const float* W2      = (const float*)d_in[8];
    const float* b2      = (const float*)d_in[9];
    const float* Wp1     = (const float*)d_in[10];
    const float* bp1     = (const float*)d_in[11];
    const float* gp      = (const float*)d_in[12];
    const float* bep     = (const float*)d_in[13];
    const float* Wp2     = (const float*)d_in[14];
    const float* bp2     = (const float*)d_in[15];
    float* out = (float*)d_out;

    int N = in_sizes[0] / F_IN;
    int E = in_sizes[2];
    float* ws = (float*)d_ws;
    int NB = (N + 255) / 256;
    int BKT = (N + 255) >> 8;   // 256 nodes per bucket (== NB)

    size_t off = 0;
    auto take = [&](size_t n) { size_t r = off; off += (n + 15) & ~(size_t)15; return r; };
    size_t o_dout_i = take((size_t)N);
    size_t o_din_i  = take((size_t)N);
    size_t o_st1    = take(32);
    size_t o_stp    = take(32);
    size_t zeroUnits = off;
    size_t o_row    = take((size_t)N + 1);
    size_t o_cursor = take((size_t)N);
    size_t o_bsum   = take((size_t)NB);
    size_t o_bcur   = take(256);
    size_t o_sorted = take((size_t)E);
    size_t o_prm    = take(1024);
    size_t o_s1b    = take((size_t)8 * N);
    size_t o_h1     = take((size_t)16 * N);
    size_t o_t12b   = take((size_t)16 * N);
    size_t o_Ub     = take((size_t)8 * N);
    size_t o_Vb     = take((size_t)8 * N);
    size_t o_binned = take((size_t)2 * E);
    size_t o_z0b    = off;
    bool store_z = ws_size >= (off + (size_t)8 * E) * 4;
    bool use_bin = (BKT <= 256) && (ws_size >= off * 4);

    hipMemsetAsync(ws, 0, zeroUnits * 4, stream);

    int* dout_i = (int*)(ws + o_dout_i);
    int* din_i  = (int*)(ws + o_din_i);
    int* rowp   = (int*)(ws + o_row);
    int* curp   = (int*)(ws + o_cursor);
    int* bsump  = (int*)(ws + o_bsum);
    int* bcurp  = (int*)(ws + o_bcur);
    int* sortedp = (int*)(ws + o_sorted);
    uint2* binnedp = (uint2*)(ws + o_binned);
    unsigned short* s1b  = (unsigned short*)(ws + o_s1b);
    unsigned short* t12b = (unsigned short*)(ws + o_t12b);
    unsigned short* Ub   = (unsigned short*)(ws + o_Ub);
    unsigned short* Vb   = (unsigned short*)(ws + o_Vb);
    unsigned short* z0h  = (unsigned short*)(ws + o_z0b);
    unsigned int* z0b    = (unsigned int*)(ws + o_z0b);

    int bE = (E + 255) / 256;
    int bN16 = (N * 16 + 255) / 256;
    int bAgg = (N * 4 + 255) / 256;

    k_deg<<<bE, 256, 0, stream>>>(src, dst, dout_i, din_i, E);
    k_scanA<<<NB, 256, 0, stream>>>(din_i, bsump, N);
    k_scanB<<<1, 256, 0, stream>>>(bsump, NB, rowp + N, bcurp);
    k_scanC<<<NB, 256, 0, stream>>>(din_i, bsump, rowp, curp, N);
    if (use_bin) {
        k_bin<<<256, 256, 0, stream>>>(src, dst, bcurp, binnedp, E, 256);
        k_scat<<<BKT, 256, 0, stream>>>(binnedp, rowp, sortedp, N);
    } else {
        k_sortedges<<<bE, 256, 0, stream>>>(src, dst, curp, sortedp, E);
    }
    k_s1<<<bN16, 256, 0, stream>>>(n_feats, W1, dout_i, s1b, N);
    k_agg1v<<<bAgg, 256, 0, stream>>>(s1b, sortedp, rowp, din_i, b1, ws + o_h1, ws + o_st1, N);
    k_fold<<<1, 256, 0, stream>>>(ws + o_st1, g1, be1, W2, b2, Wp1, ws + o_prm, N);
    k_t<<<bN16, 256, 0, stream>>>(ws + o_h1, dout_i, ws + o_prm, t12b, N);
    k_agg2v<<<bAgg, 256, 0, stream>>>(t12b, sortedp, rowp, din_i, ws + o_prm, Ub, Vb, N);

    if (store_z) {
        // natural regalloc; 4096 blocks = 8 blocks/CU available (HW caps waves by VGPR use)
        k_edge1<<<4096, 256, 0, stream>>>(e_feats, src, dst, Wp1, bp1, Ub, Vb, z0h, ws + o_stp, E);
        k_fold2<<<1, 128, 0, stream>>>(ws + o_stp, gp, bep, Wp2, bp2, ws + o_prm, E);
        k_edge2<<<bE, 256, 0, stream>>>(z0b, ws + o_prm, out, E);
    } else {
        k_edge1_stats<<<4096, 256, 0, stream>>>(e_feats, src, dst, Wp1, bp1, Ub, Vb, ws + o_stp, E);
        k_fold2<<<1, 128, 0, stream>>>(ws + o_stp, gp, bep, Wp2, bp2, ws + o_prm, E);
        k_edge2_rc<<<bE, 256, 0, stream>>>(e_feats, src, dst, Wp1, bp1, Ub, Vb, ws + o_prm, out, E);
    }
}

// Round 24
// 413.686 us; speedup vs baseline: 1.2056x; 1.0146x over previous
//
#include <hip/hip_runtime.h>
#include <hip/hip_bf16.h>
#include <math.h>
#include <stddef.h>

#define EPS 1e-5f
#define F_IN 128
#define FE 32

// prm layout (float offsets)
#define P_M1 0
#define P_M2 256
#define P_C1 512
#define P_C2 528
#define P_CU 544
#define P_CV 560
#define P_WF 576
#define P_BO 704

// ---- bf16 helpers ----
__device__ __forceinline__ float bf2f(unsigned short u) {
    return __uint_as_float(((unsigned int)u) << 16);
}
__device__ __forceinline__ unsigned short f2bf(float f) {
    unsigned int u = __float_as_uint(f);
    u = (u + 0x7fffu + ((u >> 16) & 1u)) >> 16;
    return (unsigned short)u;
}
__device__ __forceinline__ unsigned int pack2(float a, float b) {
    return (unsigned int)f2bf(a) | ((unsigned int)f2bf(b) << 16);
}
__device__ __forceinline__ float lo16(unsigned int w) { return __uint_as_float(w << 16); }
__device__ __forceinline__ float hi16(unsigned int w) { return __uint_as_float(w & 0xffff0000u); }

// ---------------- degree (int counts) ----------------
__global__ __launch_bounds__(256) void k_deg(const int* __restrict__ src, const int* __restrict__ dst,
                                             int* __restrict__ dout, int* __restrict__ din, int E) {
    int e = blockIdx.x * 256 + threadIdx.x;
    if (e < E) {
        atomicAdd(&dout[src[e]], 1);
        atomicAdd(&din[dst[e]], 1);
    }
}

// ---------------- parallel scan phase A: per-block sums (coalesced) ----------------
__global__ __launch_bounds__(256) void k_scanA(const int* __restrict__ deg, int* __restrict__ bsum, int N) {
    int i = blockIdx.x * 256 + threadIdx.x;
    int v = (i < N) ? deg[i] : 0;
    #pragma unroll
    for (int m = 1; m < 64; m <<= 1) v += __shfl_xor(v, m, 64);
    __shared__ int red[4];
    if ((threadIdx.x & 63) == 0) red[threadIdx.x >> 6] = v;
    __syncthreads();
    if (threadIdx.x == 0) bsum[blockIdx.x] = red[0] + red[1] + red[2] + red[3];
}

// ---------------- phase B: 1-block exclusive scan of block sums; also emits bucket cursors ----------------
__global__ __launch_bounds__(256) void k_scanB(int* __restrict__ bsum, int NB, int* __restrict__ rowN,
                                               int* __restrict__ bcur) {
    __shared__ int s[256];
    int per = (NB + 255) >> 8;
    int start = threadIdx.x * per;
    int end = start + per; if (end > NB) end = NB; if (start > NB) start = NB;
    int sum = 0;
    for (int i = start; i < end; ++i) sum += bsum[i];
    s[threadIdx.x] = sum;
    __syncthreads();
    for (int off = 1; off < 256; off <<= 1) {
        int t = (threadIdx.x >= off) ? s[threadIdx.x - off] : 0;
        __syncthreads();
        s[threadIdx.x] += t;
        __syncthreads();
    }
    int run = (threadIdx.x == 0) ? 0 : s[threadIdx.x - 1];
    for (int i = start; i < end; ++i) {
        int v = bsum[i];
        bsum[i] = run;
        bcur[i] = run;   // bucket b starts at exclusive prefix of its 256-node block
        run += v;
    }
    if (threadIdx.x == 255) rowN[0] = s[255];
}

// ---------------- phase C: per-block LDS scan + block offset -> row, cursor ----------------
__global__ __launch_bounds__(256) void k_scanC(const int* __restrict__ deg, const int* __restrict__ boff,
                                               int* __restrict__ row, int* __restrict__ cursor, int N) {
    __shared__ int s[256];
    int i = blockIdx.x * 256 + threadIdx.x;
    int v = (i < N) ? deg[i] : 0;
    s[threadIdx.x] = v;
    __syncthreads();
    for (int off = 1; off < 256; off <<= 1) {
        int t = (threadIdx.x >= off) ? s[threadIdx.x - off] : 0;
        __syncthreads();
        s[threadIdx.x] += t;
        __syncthreads();
    }
    int r = boff[blockIdx.x] + s[threadIdx.x] - v;
    if (i < N) { row[i] = r; cursor[i] = r; }
}

// ---------------- bin pass: group (src,dst) pairs by dst-bucket, coalesced writes ----------------
__global__ __launch_bounds__(256) void k_bin(const int* __restrict__ src, const int* __restrict__ dst,
                                             int* __restrict__ bcur, uint2* __restrict__ binned,
                                             int E, int nBlocks) {
    __shared__ int hist[256], base[256], offs[256];
    int chunk = (E + nBlocks - 1) / nBlocks;
    int start = blockIdx.x * chunk;
    int end = start + chunk; if (end > E) end = E;
    hist[threadIdx.x] = 0; offs[threadIdx.x] = 0;
    __syncthreads();
    for (int i = start + threadIdx.x; i < end; i += 256)
        atomicAdd(&hist[dst[i] >> 8], 1);
    __syncthreads();
    int h = hist[threadIdx.x];
    base[threadIdx.x] = h ? atomicAdd(&bcur[threadIdx.x], h) : 0;
    __syncthreads();
    for (int i = start + threadIdx.x; i < end; i += 256) {
        int d = dst[i], b = d >> 8;
        int p = base[b] + atomicAdd(&offs[b], 1);
        binned[p] = make_uint2((unsigned int)src[i], (unsigned int)d);
    }
}

// ---------------- scatter pass: one WG per bucket, LDS cursors, L2-local writes ----------------
__global__ __launch_bounds__(256) void k_scat(const uint2* __restrict__ binned, const int* __restrict__ row,
                                              int* __restrict__ sorted_src, int N) {
    __shared__ int cur[256];
    int nb = blockIdx.x << 8;
    int hi = nb + 256; if (hi > N) hi = N;
    if (nb + threadIdx.x < N) cur[threadIdx.x] = row[nb + threadIdx.x];
    __syncthreads();
    int eStart = row[nb], eEnd = row[hi];
    for (int i = eStart + threadIdx.x; i < eEnd; i += 256) {
        uint2 p = binned[i];
        int pos = atomicAdd(&cur[(int)p.y - nb], 1);
        sorted_src[pos] = (int)p.x;
    }
}

// ---------------- counting-sort fallback (no-bin path) ----------------
__global__ __launch_bounds__(256) void k_sortedges(const int* __restrict__ src, const int* __restrict__ dst,
                                                   int* __restrict__ cursor, int* __restrict__ sorted_src, int E) {
    int e = blockIdx.x * 256 + threadIdx.x;
    if (e < E) {
        int p = atomicAdd(&cursor[dst[e]], 1);
        sorted_src[p] = src[e];
    }
}

// ---------------- s1 = (n_feats @ W1) * rsqrt(deg_out)  (bf16 out), LDS-staged rows ----------------
// 16 nodes/block. Rows staged via coalesced float4 (2 loads/thread) instead of 16x-redundant
// scalar broadcast reads; compute from LDS (b128 broadcast reads, conflict-free).
__global__ __launch_bounds__(256) void k_s1(const float* __restrict__ x, const float* __restrict__ W1,
                                            const int* __restrict__ dout, unsigned short* __restrict__ s1b, int N) {
    __shared__ float w[F_IN * 16];
    __shared__ __align__(16) float xs[16][F_IN];
    for (int i = threadIdx.x; i < (F_IN * 16) / 4; i += 256)
        ((float4*)w)[i] = ((const float4*)W1)[i];
    int n0 = blockIdx.x * 16;
    int nrows = N - n0; if (nrows > 16) nrows = 16;
    for (int i = threadIdx.x; i < nrows * 32; i += 256) {
        int r = i >> 5, c = i & 31;
        ((float4*)xs[r])[c] = ((const float4*)(x + (size_t)(n0 + r) * F_IN))[c];
    }
    __syncthreads();
    int n = n0 + (threadIdx.x >> 4), j = threadIdx.x & 15;
    if (n >= N) return;
    const float4* row = (const float4*)xs[threadIdx.x >> 4];
    float acc = 0.f;
    #pragma unroll
    for (int q = 0; q < 32; ++q) {
        float4 x4 = row[q];
        acc += x4.x * w[(4 * q + 0) * 16 + j] + x4.y * w[(4 * q + 1) * 16 + j]
             + x4.z * w[(4 * q + 2) * 16 + j] + x4.w * w[(4 * q + 3) * 16 + j];
    }
    s1b[(size_t)n * 16 + j] = f2bf(acc * rsqrtf(fmaxf((float)dout[n], 1.0f)));
}

// ---------------- vectorized agg1: 4 lanes/node x 4ch, uint2 gather; relu + BN1 stats ----------------
__global__ __launch_bounds__(256) void k_agg1v(const unsigned short* __restrict__ s1b,
                                               const int* __restrict__ sorted_src, const int* __restrict__ row,
                                               const int* __restrict__ din, const float* __restrict__ b1,
                                               float* __restrict__ h1, float* __restrict__ st1, int N) {
    __shared__ float lsum[16], lsq[16];
    if (threadIdx.x < 16) { lsum[threadIdx.x] = 0.f; lsq[threadIdx.x] = 0.f; }
    __syncthreads();
    int t = blockIdx.x * 256 + threadIdx.x;
    int n = t >> 2, q = t & 3;
    float v0 = 0.f, v1 = 0.f, v2 = 0.f, v3 = 0.f;
    if (n < N) {
        float a0 = 0.f, a1 = 0.f, a2 = 0.f, a3 = 0.f;
        int b = row[n], e = row[n + 1];
        for (int i = b; i < e; ++i) {
            int s = sorted_src[i];
            uint2 w = *(const uint2*)(s1b + (size_t)s * 16 + q * 4);
            a0 += lo16(w.x); a1 += hi16(w.x);
            a2 += lo16(w.y); a3 += hi16(w.y);
        }
        float div = rsqrtf(fmaxf((float)din[n], 1.f));
        v0 = fmaxf(a0 * div + b1[q * 4 + 0], 0.f);
        v1 = fmaxf(a1 * div + b1[q * 4 + 1], 0.f);
        v2 = fmaxf(a2 * div + b1[q * 4 + 2], 0.f);
        v3 = fmaxf(a3 * div + b1[q * 4 + 3], 0.f);
        *(float4*)(h1 + (size_t)n * 16 + q * 4) = make_float4(v0, v1, v2, v3);
    }
    float s0 = v0, s1 = v1, s2 = v2, s3 = v3;
    float q0 = v0 * v0, q1 = v1 * v1, q2 = v2 * v2, q3 = v3 * v3;
    #pragma unroll
    for (int m = 4; m < 64; m <<= 1) {
        s0 += __shfl_xor(s0, m, 64); q0 += __shfl_xor(q0, m, 64);
        s1 += __shfl_xor(s1, m, 64); q1 += __shfl_xor(q1, m, 64);
        s2 += __shfl_xor(s2, m, 64); q2 += __shfl_xor(q2, m, 64);
        s3 += __shfl_xor(s3, m, 64); q3 += __shfl_xor(q3, m, 64);
    }
    if ((threadIdx.x & 63) < 4) {
        int j = (threadIdx.x & 3) * 4;
        atomicAdd(&lsum[j + 0], s0); atomicAdd(&lsq[j + 0], q0);
        atomicAdd(&lsum[j + 1], s1); atomicAdd(&lsq[j + 1], q1);
        atomicAdd(&lsum[j + 2], s2); atomicAdd(&lsq[j + 2], q2);
        atomicAdd(&lsum[j + 3], s3); atomicAdd(&lsq[j + 3], q3);
    }
    __syncthreads();
    if (threadIdx.x < 16) {
        atomicAdd(&st1[threadIdx.x], lsum[threadIdx.x]);
        atomicAdd(&st1[16 + threadIdx.x], lsq[threadIdx.x]);
    }
}

// ---------------- fold BN1 + W2 + Wp1 slices into M1,M2 + vectors ----------------
__global__ __launch_bounds__(256) void k_fold(const float* __restrict__ st, const float* __restrict__ g1,
                                              const float* __restrict__ be1, const float* __restrict__ W2,
                                              const float* __restrict__ b2, const float* __restrict__ Wp1,
                                              float* __restrict__ prm, int N) {
    __shared__ float scale[16], shift[16], d2[64];
    int t = threadIdx.x;
    if (t < 16) {
        float mu = st[t] / (float)N;
        float var = st[16 + t] / (float)N - mu * mu;
        float sc = g1[t] * rsqrtf(var + EPS);
        scale[t] = sc;
        shift[t] = be1[t] - mu * sc;
    }
    __syncthreads();
    if (t < 64) {
        float acc = 0.f;
        #pragma unroll
        for (int j = 0; j < 16; ++j) acc += shift[j] * W2[j * 64 + t];
        d2[t] = acc;
    }
    __syncthreads();
    {
        int j1 = t >> 4, j2 = t & 15;
        float m1 = 0.f, m2 = 0.f;
        float sc = scale[j1];
        for (int c = 0; c < 64; ++c) {
            float w = sc * W2[j1 * 64 + c];
            m1 += w * Wp1[(32 + c) * 16 + j2];
            m2 += w * Wp1[(96 + c) * 16 + j2];
        }
        prm[P_M1 + j1 * 16 + j2] = m1;
        prm[P_M2 + j1 * 16 + j2] = m2;
    }
    if (t < 16) {
        float a = 0.f, b = 0.f, u = 0.f, v = 0.f;
        for (int c = 0; c < 64; ++c) {
            float wb = Wp1[(32 + c) * 16 + t], wc = Wp1[(96 + c) * 16 + t];
            a += d2[c] * wb; b += d2[c] * wc;
            u += b2[c] * wb; v += b2[c] * wc;
        }
        prm[P_C1 + t] = a; prm[P_C2 + t] = b;
        prm[P_CU + t] = u; prm[P_CV + t] = v;
    }
}

// ---------------- t12 = rsqrt(deg_out)*(h1@M1+c1) || (h1@M2+c2)  (interleaved 32 bf16/node) ----------------
__global__ __launch_bounds__(256) void k_t(const float* __restrict__ h1, const int* __restrict__ dout,
                                           const float* __restrict__ prm, unsigned short* __restrict__ t12b, int N) {
    __shared__ float M1[256], M2[256], c1[16], c2[16];
    for (int i = threadIdx.x; i < 256; i += 256) { M1[i] = prm[P_M1 + i]; M2[i] = prm[P_M2 + i]; }
    if (threadIdx.x < 16) { c1[threadIdx.x] = prm[P_C1 + threadIdx.x]; c2[threadIdx.x] = prm[P_C2 + threadIdx.x]; }
    __syncthreads();
    int t = blockIdx.x * 256 + threadIdx.x;
    int n = t >> 4, j = t & 15;
    if (n >= N) return;
    float div = rsqrtf(fmaxf((float)dout[n], 1.f));
    const float* h = h1 + (size_t)n * 16;
    float a = c1[j], b = c2[j];
    #pragma unroll
    for (int k = 0; k < 16; ++k) { float x = h[k]; a += x * M1[k * 16 + j]; b += x * M2[k * 16 + j]; }
    t12b[(size_t)n * 32 + j] = f2bf(a * div);
    t12b[(size_t)n * 32 + 16 + j] = f2bf(b * div);
}

// ---------------- vectorized agg2: 4 lanes/node x 8ch of 32, uint4 gather -> U,V bf16 ----------------
__global__ __launch_bounds__(256) void k_agg2v(const unsigned short* __restrict__ t12b,
                                               const int* __restrict__ sorted_src, const int* __restrict__ row,
                                               const int* __restrict__ din, const float* __restrict__ prm,
                                               unsigned short* __restrict__ Ub, unsigned short* __restrict__ Vb,
                                               int N) {
    int t = blockIdx.x * 256 + threadIdx.x;
    int n = t >> 2, q = t & 3;
    if (n >= N) return;
    float a0 = 0.f, a1 = 0.f, a2 = 0.f, a3 = 0.f, a4 = 0.f, a5 = 0.f, a6 = 0.f, a7 = 0.f;
    int b = row[n], e = row[n + 1];
    for (int i = b; i < e; ++i) {
        int s = sorted_src[i];
        uint4 w = *(const uint4*)(t12b + (size_t)s * 32 + q * 8);
        a0 += lo16(w.x); a1 += hi16(w.x);
        a2 += lo16(w.y); a3 += hi16(w.y);
        a4 += lo16(w.z); a5 += hi16(w.z);
        a6 += lo16(w.w); a7 += hi16(w.w);
    }
    float div = rsqrtf(fmaxf((float)din[n], 1.f));
    const float* cb = prm + ((q < 2) ? P_CU : P_CV) + (q & 1) * 8;
    uint4 ov;
    ov.x = pack2(a0 * div + cb[0], a1 * div + cb[1]);
    ov.y = pack2(a2 * div + cb[2], a3 * div + cb[3]);
    ov.z = pack2(a4 * div + cb[4], a5 * div + cb[5]);
    ov.w = pack2(a6 * div + cb[6], a7 * div + cb[7]);
    unsigned short* dstp = ((q < 2) ? Ub : Vb) + (size_t)n * 16 + (q & 1) * 8;
    *(uint4*)dstp = ov;
}

// ---------------- edge pass 1: wave-local LDS staging + ds_read_b128, natural regalloc ----------------
__global__ __launch_bounds__(256) void k_edge1(const float* __restrict__ ef, const int* __restrict__ src,
                                               const int* __restrict__ dst, const float* __restrict__ Wp1,
                                               const float* __restrict__ bp1,
                                               const unsigned short* __restrict__ Ub,
                                               const unsigned short* __restrict__ Vb,
                                               unsigned short* __restrict__ z0h,
                                               float* __restrict__ statsp, int E) {
    __shared__ float red[32];
    __shared__ __align__(16) float efs[4][4][36];   // [wave][edge][padded row]
    if (threadIdx.x < 32) red[threadIdx.x] = 0.f;
    __syncthreads();

    int l = threadIdx.x & 63;
    int w = threadIdx.x >> 6;
    int g = l >> 4, j = l & 15;

    float wcol[32];
    #pragma unroll
    for (int k = 0; k < 32; ++k) wcol[k] = Wp1[k * 16 + j];
    float bj = bp1[j];

    int wv = (blockIdx.x * 256 + threadIdx.x) >> 6;
    int nW = (gridDim.x * 256) >> 6;
    float sum = 0.f, sq = 0.f;

    #pragma unroll 1
    for (int base = wv * 4; base < E; base += nW * 4) {
        int e = base + g;
        float2 v = make_float2(0.f, 0.f);
        if (e < E) v = ((const float2*)(ef + (size_t)e * FE))[j];
        *(float2*)&efs[w][g][2 * j] = v;           // ds_write_b64, 2-way bank alias (free)
        if (e < E) {
            int s = src[e], d = dst[e];
            float z = bj + bf2f(Ub[s * 16 + j]) + bf2f(Vb[d * 16 + j]);
            #pragma unroll
            for (int q = 0; q < 8; ++q) {
                float4 x = *(const float4*)&efs[w][g][4 * q];   // ds_read_b128 broadcast
                z += x.x * wcol[4 * q + 0] + x.y * wcol[4 * q + 1]
                   + x.z * wcol[4 * q + 2] + x.w * wcol[4 * q + 3];
            }
            z0h[(size_t)e * 16 + j] = f2bf(z);
            sum += z; sq += z * z;
        }
    }

    sum += __shfl_xor(sum, 16, 64); sq += __shfl_xor(sq, 16, 64);
    sum += __shfl_xor(sum, 32, 64); sq += __shfl_xor(sq, 32, 64);
    if (l < 16) { atomicAdd(&red[j], sum); atomicAdd(&red[16 + j], sq); }
    __syncthreads();
    if (threadIdx.x < 16) {
        atomicAdd(&statsp[threadIdx.x], red[threadIdx.x]);
        atomicAdd(&statsp[16 + threadIdx.x], red[16 + threadIdx.x]);
    }
}

// ---------------- fold BN2 into Wp2 ----------------
__global__ __launch_bounds__(128) void k_fold2(const float* __restrict__ stp, const float* __restrict__ gp,
                                               const float* __restrict__ bep, const float* __restrict__ Wp2,
                                               const float* __restrict__ bp2, float* __restrict__ prm, int E) {
    __shared__ float sc[16], sh[16];
    int t = threadIdx.x;
    if (t < 16) {
        float mu = stp[t] / (float)E;
        float var = stp[16 + t] / (float)E - mu * mu;
        float s = gp[t] * rsqrtf(var + EPS);
        sc[t] = s;
        sh[t] = bep[t] - mu * s;
    }
    __syncthreads();
    if (t < 128) { int j = t >> 3, k = t & 7; prm[P_WF + t] = sc[j] * Wp2[j * 8 + k]; }
    if (t < 8) {
        float a = bp2[t];
        #pragma unroll
        for (int j = 0; j < 16; ++j) a += sh[j] * Wp2[j * 8 + t];
        prm[P_BO + t] = a;
    }
}

// ---------------- logits + log_softmax ----------------
__device__ __forceinline__ void logits_out(int e, const float* z, const float* wf, const float* bo,
                                           float* __restrict__ out) {
    float l[8];
    #pragma unroll
    for (int k = 0; k < 8; ++k) l[k] = bo[k];
    #pragma unroll
    for (int j = 0; j < 16; ++j) {
        float x = z[j];
        #pragma unroll
        for (int k = 0; k < 8; ++k) l[k] += x * wf[j * 8 + k];
    }
    float m = l[0];
    #pragma unroll
    for (int k = 1; k < 8; ++k) m = fmaxf(m, l[k]);
    float s = 0.f;
    #pragma unroll
    for (int k = 0; k < 8; ++k) s += expf(l[k] - m);
    float r = m + logf(s);
    float4* op = (float4*)(out + (size_t)e * 8);
    op[0] = make_float4(l[0] - r, l[1] - r, l[2] - r, l[3] - r);
    op[1] = make_float4(l[4] - r, l[5] - r, l[6] - r, l[7] - r);
}

// ---------------- edge pass 2 (read bf16 z0) ----------------
__global__ __launch_bounds__(256) void k_edge2(const unsigned int* __restrict__ z0b,
                                               const float* __restrict__ prm,
                                               float* __restrict__ out, int E) {
    __shared__ float wf[128], bo[8];
    if (threadIdx.x < 128) wf[threadIdx.x] = prm[P_WF + threadIdx.x];
    if (threadIdx.x < 8) bo[threadIdx.x] = prm[P_BO + threadIdx.x];
    __syncthreads();
    int e = blockIdx.x * 256 + threadIdx.x;
    if (e >= E) return;
    const uint4* zp = (const uint4*)(z0b + (size_t)e * 8);
    uint4 a0 = zp[0], a1 = zp[1];
    unsigned int w[8] = {a0.x, a0.y, a0.z, a0.w, a1.x, a1.y, a1.z, a1.w};
    float z[16];
    #pragma unroll
    for (int q = 0; q < 8; ++q) {
        z[2 * q]     = __uint_as_float(w[q] << 16);
        z[2 * q + 1] = __uint_as_float(w[q] & 0xffff0000u);
    }
    logits_out(e, z, wf, bo, out);
}

// ---------------- fallback (ws too small): LDS-staged edge1 stats-only + recompute pass 2 ----------------
__global__ __launch_bounds__(256) void k_edge1_stats(const float* __restrict__ ef, const int* __restrict__ src,
                                                     const int* __restrict__ dst, const float* __restrict__ Wp1,
                                                     const float* __restrict__ bp1,
                                                     const unsigned short* __restrict__ Ub,
                                                     const unsigned short* __restrict__ Vb,
                                                     float* __restrict__ statsp, int E) {
    __shared__ float red[32];
    __shared__ __align__(16) float efs[4][4][36];
    if (threadIdx.x < 32) red[threadIdx.x] = 0.f;
    __syncthreads();
    int l = threadIdx.x & 63;
    int w = threadIdx.x >> 6;
    int g = l >> 4, j = l & 15;
    float wcol[32];
    #pragma unroll
    for (int k = 0; k < 32; ++k) wcol[k] = Wp1[k * 16 + j];
    float bj = bp1[j];
    int wv = (blockIdx.x * 256 + threadIdx.x) >> 6;
    int nW = (gridDim.x * 256) >> 6;
    float sum = 0.f, sq = 0.f;
    #pragma unroll 1
    for (int base = wv * 4; base < E; base += nW * 4) {
        int e = base + g;
        float2 v = make_float2(0.f, 0.f);
        if (e < E) v = ((const float2*)(ef + (size_t)e * FE))[j];
        *(float2*)&efs[w][g][2 * j] = v;
        if (e < E) {
            int s = src[e], d = dst[e];
            float z = bj + bf2f(Ub[s * 16 + j]) + bf2f(Vb[d * 16 + j]);
            #pragma unroll
            for (int q = 0; q < 8; ++q) {
                float4 x = *(const float4*)&efs[w][g][4 * q];
                z += x.x * wcol[4 * q + 0] + x.y * wcol[4 * q + 1]
                   + x.z * wcol[4 * q + 2] + x.w * wcol[4 * q + 3];
            }
            sum += z; sq += z * z;
        }
    }
    sum += __shfl_xor(sum, 16, 64); sq += __shfl_xor(sq, 16, 64);
    sum += __shfl_xor(sum, 32, 64); sq += __shfl_xor(sq, 32, 64);
    if (l < 16) { atomicAdd(&red[j], sum); atomicAdd(&red[16 + j], sq); }
    __syncthreads();
    if (threadIdx.x < 16) {
        atomicAdd(&statsp[threadIdx.x], red[threadIdx.x]);
        atomicAdd(&statsp[16 + threadIdx.x], red[16 + threadIdx.x]);
    }
}

__global__ __launch_bounds__(256, 2) void k_edge2_rc(const float* __restrict__ ef, const int* __restrict__ src,
                                                     const int* __restrict__ dst, const float* __restrict__ Wp1,
                                                     const float* __restrict__ bp1,
                                                     const unsigned short* __restrict__ Ub,
                                                     const unsigned short* __restrict__ Vb,
                                                     const float* __restrict__ prm,
                                                     float* __restrict__ out, int E) {
    __shared__ float wa[FE * 16];
    __shared__ float bb[16];
    __shared__ float wf[128], bo[8];
    for (int i = threadIdx.x; i < FE * 16; i += 256) wa[i] = Wp1[i];
    if (threadIdx.x < 16) bb[threadIdx.x] = bp1[threadIdx.x];
    if (threadIdx.x < 128) wf[threadIdx.x] = prm[P_WF + threadIdx.x];
    if (threadIdx.x < 8) bo[threadIdx.x] = prm[P_BO + threadIdx.x];
    __syncthreads();
    int e = blockIdx.x * 256 + threadIdx.x;
    if (e >= E) return;
    float z[16];
    {
        int s = src[e], d = dst[e];
        const uint4* up = (const uint4*)(Ub + (size_t)s * 16);
        const uint4* vp = (const uint4*)(Vb + (size_t)d * 16);
        #pragma unroll
        for (int h = 0; h < 2; ++h) {
            uint4 ua = up[h], va = vp[h];
            unsigned int uu[4] = {ua.x, ua.y, ua.z, ua.w};
            unsigned int vv[4] = {va.x, va.y, va.z, va.w};
            #pragma unroll
            for (int q = 0; q < 4; ++q) {
                int jj = h * 8 + 2 * q;
                z[jj]     = bb[jj]     + __uint_as_float(uu[q] << 16)          + __uint_as_float(vv[q] << 16);
                z[jj + 1] = bb[jj + 1] + __uint_as_float(uu[q] & 0xffff0000u) + __uint_as_float(vv[q] & 0xffff0000u);
            }
        }
    }
    const float4* ep = (const float4*)(ef + (size_t)e * FE);
    #pragma unroll
    for (int q = 0; q < 8; ++q) {
        float4 x4 = ep[q];
        float xs[4] = {x4.x, x4.y, x4.z, x4.w};
        #pragma unroll
        for (int kk = 0; kk < 4; ++kk) {
            float x = xs[kk];
            #pragma unroll
            for (int jj = 0; jj < 16; ++jj) z[jj] += x * wa[(q * 4 + kk) * 16 + jj];
        }
    }
    logits_out(e, z, wf, bo, out);
}

extern "C" void kernel_launch(void* const* d_in, const int* in_sizes, int n_in,
                              void* d_out, int out_size, void* d_ws, size_t ws_size,
                              hipStream_t stream) {
    const float* n_feats = (const float*)d_in[0];
    const float* e_feats = (const float*)d_in[1];
    const int*   src     = (const int*)d_in[2];
    const int*   dst     = (const int*)d_in[3];
    const float* W1      = (const float*)d_in[4];
    const float* b1      = (const float*)d_in[5];
    const float* g1      = (const float*)d_in[6];
    const float* be1     = (const float*)d_in[7];
    const float* W2      = (const float*)d_in[8];
    const float* b2      = (const float*)d_in[9];
    const float* Wp1     = (const float*)d_in[10];
    const float* bp1     = (const float*)d_in[11];
    const float* gp      = (const float*)d_in[12];
    const float* bep     = (const float*)d_in[13];
    const float* Wp2     = (const float*)d_in[14];
    const float* bp2     = (const float*)d_in[15];
    float* out = (float*)d_out;

    int N = in_sizes[0] / F_IN;
    int E = in_sizes[2];
    float* ws = (float*)d_ws;
    int NB = (N + 255) / 256;
    int BKT = (N + 255) >> 8;   // 256 nodes per bucket (== NB)

    size_t off = 0;
    auto take = [&](size_t n) { size_t r = off; off += (n + 15) & ~(size_t)15; return r; };
    size_t o_dout_i = take((size_t)N);
    size_t o_din_i  = take((size_t)N);
    size_t o_st1    = take(32);
    size_t o_stp    = take(32);
    size_t zeroUnits = off;
    size_t o_row    = take((size_t)N + 1);
    size_t o_cursor = take((size_t)N);
    size_t o_bsum   = take((size_t)NB);
    size_t o_bcur   = take(256);
    size_t o_sorted = take((size_t)E);
    size_t o_prm    = take(1024);
    size_t o_s1b    = take((size_t)8 * N);
    size_t o_h1     = take((size_t)16 * N);
    size_t o_t12b   = take((size_t)16 * N);
    size_t o_Ub     = take((size_t)8 * N);
    size_t o_Vb     = take((size_t)8 * N);
    size_t o_binned = take((size_t)2 * E);
    size_t o_z0b    = off;
    bool store_z = ws_size >= (off + (size_t)8 * E) * 4;
    bool use_bin = (BKT <= 256) && (ws_size >= off * 4);

    hipMemsetAsync(ws, 0, zeroUnits * 4, stream);

    int* dout_i = (int*)(ws + o_dout_i);
    int* din_i  = (int*)(ws + o_din_i);
    int* rowp   = (int*)(ws + o_row);
    int* curp   = (int*)(ws + o_cursor);
    int* bsump  = (int*)(ws + o_bsum);
    int* bcurp  = (int*)(ws + o_bcur);
    int* sortedp = (int*)(ws + o_sorted);
    uint2* binnedp = (uint2*)(ws + o_binned);
    unsigned short* s1b  = (unsigned short*)(ws + o_s1b);
    unsigned short* t12b = (unsigned short*)(ws + o_t12b);
    unsigned short* Ub   = (unsigned short*)(ws + o_Ub);
    unsigned short* Vb   = (unsigned short*)(ws + o_Vb);
    unsigned short* z0h  = (unsigned short*)(ws + o_z0b);
    unsigned int* z0b    = (unsigned int*)(ws + o_z0b);

    int bE = (E + 255) / 256;
    int bN16 = (N * 16 + 255) / 256;
    int bAgg = (N * 4 + 255) / 256;
    int bS1 = (N + 15) / 16;

    k_deg<<<bE, 256, 0, stream>>>(src, dst, dout_i, din_i, E);
    k_scanA<<<NB, 256, 0, stream>>>(din_i, bsump, N);
    k_scanB<<<1, 256, 0, stream>>>(bsump, NB, rowp + N, bcurp);
    k_scanC<<<NB, 256, 0, stream>>>(din_i, bsump, rowp, curp, N);
    if (use_bin) {
        k_bin<<<256, 256, 0, stream>>>(src, dst, bcurp, binnedp, E, 256);
        k_scat<<<BKT, 256, 0, stream>>>(binnedp, rowp, sortedp, N);
    } else {
        k_sortedges<<<bE, 256, 0, stream>>>(src, dst, curp, sortedp, E);
    }
    k_s1<<<bS1, 256, 0, stream>>>(n_feats, W1, dout_i, s1b, N);
    k_agg1v<<<bAgg, 256, 0, stream>>>(s1b, sortedp, rowp, din_i, b1, ws + o_h1, ws + o_st1, N);
    k_fold<<<1, 256, 0, stream>>>(ws + o_st1, g1, be1, W2, b2, Wp1, ws + o_prm, N);
    k_t<<<bN16, 256, 0, stream>>>(ws + o_h1, dout_i, ws + o_prm, t12b, N);
    k_agg2v<<<bAgg, 256, 0, stream>>>(t12b, sortedp, rowp, din_i, ws + o_prm, Ub, Vb, N);

    if (store_z) {
        k_edge1<<<4096, 256, 0, stream>>>(e_feats, src, dst, Wp1, bp1, Ub, Vb, z0h, ws + o_stp, E);
        k_fold2<<<1, 128, 0, stream>>>(ws + o_stp, gp, bep, Wp2, bp2, ws + o_prm, E);
        k_edge2<<<bE, 256, 0, stream>>>(z0b, ws + o_prm, out, E);
    } else {
        k_edge1_stats<<<4096, 256, 0, stream>>>(e_feats, src, dst, Wp1, bp1, Ub, Vb, ws + o_stp, E);
        k_fold2<<<1, 128, 0, stream>>>(ws + o_stp, gp, bep, Wp2, bp2, ws + o_prm, E);
        k_edge2_rc<<<bE, 256, 0, stream>>>(e_feats, src, dst, Wp1, bp1, Ub, Vb, ws + o_prm, out, E);
    }
}